// Round 9
// baseline (501.502 us; speedup 1.0000x reference)
//
#include <hip/hip_runtime.h>

#define NN 60000
#define NE 300000
typedef unsigned short ush;

static inline int cdiv(int a, int b) { return (a + b - 1) / b; }

__device__ inline unsigned ord_enc(float x) {
  unsigned u = __float_as_uint(x);
  return (u & 0x80000000u) ? ~u : (u | 0x80000000u);
}
__device__ inline float ord_dec(unsigned u) {
  return __uint_as_float((u & 0x80000000u) ? (u & 0x7fffffffu) : ~u);
}
__device__ inline float bf2f(unsigned u16) { return __uint_as_float(u16 << 16); }
__device__ inline ush f2bf(float x) {
  unsigned u = __float_as_uint(x);
  return (ush)((u + 0x7FFFu + ((u >> 16) & 1u)) >> 16);
}
__device__ inline unsigned pack2(float lo, float hi) {
  return ((unsigned)f2bf(hi) << 16) | (unsigned)f2bf(lo);
}

// ================= CSR build (generic over key array) =================
__global__ void deg_kernel(const int* __restrict__ key, int* __restrict__ deg) {
  int e = blockIdx.x * blockDim.x + threadIdx.x;
  if (e < NE) atomicAdd(deg + key[e], 1);
}

__global__ void scan1_kernel(const int* __restrict__ deg, int* __restrict__ rowptr,
                             int* __restrict__ partial) {
  __shared__ int s[256];
  int i = blockIdx.x * 256 + threadIdx.x;
  int v = (i < NN) ? deg[i] : 0;
  s[threadIdx.x] = v;
  __syncthreads();
  for (int off = 1; off < 256; off <<= 1) {
    int t = (threadIdx.x >= off) ? s[threadIdx.x - off] : 0;
    __syncthreads();
    s[threadIdx.x] += t;
    __syncthreads();
  }
  if (i < NN) rowptr[i] = s[threadIdx.x] - v;
  if (threadIdx.x == 255) partial[blockIdx.x] = s[255];
}

__global__ void scan2_kernel(int* __restrict__ partial, int nb) {
  __shared__ int s[256];
  int v = (threadIdx.x < nb) ? partial[threadIdx.x] : 0;
  s[threadIdx.x] = v;
  __syncthreads();
  for (int off = 1; off < 256; off <<= 1) {
    int t = (threadIdx.x >= off) ? s[threadIdx.x - off] : 0;
    __syncthreads();
    s[threadIdx.x] += t;
    __syncthreads();
  }
  if (threadIdx.x < nb) partial[threadIdx.x] = s[threadIdx.x] - v;
}

__global__ void scan3_kernel(int* __restrict__ rowptr, const int* __restrict__ partial,
                             int* __restrict__ cursor) {
  int i = blockIdx.x * 256 + threadIdx.x;
  if (i < NN) {
    int r = rowptr[i] + partial[blockIdx.x];
    rowptr[i] = r;
    cursor[i] = r;
  }
}

// dst-CSR scatter: src_s (source of each dst-sorted edge) + eid_s (original edge id)
__global__ void scatter_dst_kernel(const int* __restrict__ src, const int* __restrict__ dst,
                                   int* __restrict__ cursor, int* __restrict__ src_s,
                                   int* __restrict__ eid_s) {
  int e = blockIdx.x * blockDim.x + threadIdx.x;
  if (e >= NE) return;
  int j = atomicAdd(cursor + dst[e], 1);
  src_s[j] = src[e];
  eid_s[j] = e;
}

// src-CSR scatter: eid_ss (edge id per src-sorted slot) + pos_s (src-slot of each edge)
__global__ void scatter_src_kernel(const int* __restrict__ src, int* __restrict__ cursor,
                                   int* __restrict__ eid_ss, int* __restrict__ pos_s) {
  int e = blockIdx.x * blockDim.x + threadIdx.x;
  if (e >= NE) return;
  int j = atomicAdd(cursor + src[e], 1);
  eid_ss[j] = e;
  pos_s[e] = j;
}

// ---------------- fold: precompute folded weight products (7424 dots of length 64) -------
__global__ void fold_kernel(const float* __restrict__ fp_w, const float* __restrict__ fp_b,
                            const float* __restrict__ ep_w, const float* __restrict__ ep_b,
                            const float* __restrict__ fij, const float* __restrict__ ebias,
                            const float* __restrict__ ni, const float* __restrict__ nj,
                            const float* __restrict__ node, float* __restrict__ fold) {
  int t = blockIdx.x * blockDim.x + threadIdx.x;
  if (t >= 7424) return;
  int o = t & 63;
  const float* A;
  const float* B;
  float init = 0.f;
  if (t < 1024)      { A = ep_w + (size_t)(t >> 6) * 64; B = fij + o; }
  else if (t < 1088) { A = ep_b; B = fij + o; init = ebias[o]; }
  else if (t < 3136) { A = fp_w + (size_t)((t - 1088) >> 6) * 64; B = ni + o; }
  else if (t < 5184) { A = fp_w + (size_t)((t - 3136) >> 6) * 64; B = nj + o; }
  else if (t < 7232) { A = fp_w + (size_t)((t - 5184) >> 6) * 64; B = node + o; }
  else if (t < 7296) { A = fp_b; B = ni + o; }
  else if (t < 7360) { A = fp_b; B = nj + o; }
  else               { A = fp_b; B = node + o; }
  float a = init;
  for (int i = 0; i < 64; ++i) a = fmaf(A[i], B[(size_t)i * 64], a);
  fold[t] = a;
}

// ---------------- tiled GEMM (rows x K) @ (K x 64) -> bf16 out; 3 weight sets ------------
template <int K, bool BIAS>
__global__ __launch_bounds__(256, 2) void gemm3_kernel(
    const float* __restrict__ A, const float* __restrict__ W0, const float* __restrict__ W1,
    const float* __restrict__ W2, const float* __restrict__ b0, const float* __restrict__ b1,
    const float* __restrict__ b2, ush* __restrict__ o0, ush* __restrict__ o1,
    ush* __restrict__ o2, int rows) {
  __shared__ float sA[128][K + 1];
  __shared__ float sW[K][64];
  const float* W = blockIdx.y == 0 ? W0 : blockIdx.y == 1 ? W1 : W2;
  const float* bb = blockIdx.y == 0 ? b0 : blockIdx.y == 1 ? b1 : b2;
  ush* out = blockIdx.y == 0 ? o0 : blockIdx.y == 1 ? o1 : o2;
  int t = threadIdx.x;
  int r0 = blockIdx.x * 128;
  for (int i = t; i < K * 16; i += 256) ((float4*)sW)[i] = ((const float4*)W)[i];
  for (int i = t; i < 128 * (K / 4); i += 256) {
    int rr = i / (K / 4), cc = i % (K / 4);
    float4 v = (r0 + rr < rows) ? ((const float4*)(A + (size_t)(r0 + rr) * K))[cc]
                                : make_float4(0.f, 0.f, 0.f, 0.f);
    sA[rr][cc * 4 + 0] = v.x;
    sA[rr][cc * 4 + 1] = v.y;
    sA[rr][cc * 4 + 2] = v.z;
    sA[rr][cc * 4 + 3] = v.w;
  }
  __syncthreads();
  int rg = t >> 3, cg = t & 7;
  float acc[4][8];
#pragma unroll
  for (int i = 0; i < 4; ++i)
#pragma unroll
    for (int j = 0; j < 8; ++j) acc[i][j] = 0.f;
#pragma unroll 8
  for (int k = 0; k < K; ++k) {
    float a0 = sA[rg * 4 + 0][k], a1 = sA[rg * 4 + 1][k];
    float a2 = sA[rg * 4 + 2][k], a3 = sA[rg * 4 + 3][k];
    float4 wA = *(const float4*)&sW[k][cg * 8];
    float4 wB = *(const float4*)&sW[k][cg * 8 + 4];
#pragma unroll
    for (int i = 0; i < 4; ++i) {
      float a = i == 0 ? a0 : i == 1 ? a1 : i == 2 ? a2 : a3;
      acc[i][0] = fmaf(a, wA.x, acc[i][0]); acc[i][1] = fmaf(a, wA.y, acc[i][1]);
      acc[i][2] = fmaf(a, wA.z, acc[i][2]); acc[i][3] = fmaf(a, wA.w, acc[i][3]);
      acc[i][4] = fmaf(a, wB.x, acc[i][4]); acc[i][5] = fmaf(a, wB.y, acc[i][5]);
      acc[i][6] = fmaf(a, wB.z, acc[i][6]); acc[i][7] = fmaf(a, wB.w, acc[i][7]);
    }
  }
  float bv[8];
#pragma unroll
  for (int j = 0; j < 8; ++j) bv[j] = BIAS ? bb[cg * 8 + j] : 0.f;
#pragma unroll
  for (int i = 0; i < 4; ++i) {
    int r = r0 + rg * 4 + i;
    if (r < rows) {
      uint4 pv;
      pv.x = pack2(acc[i][0] + bv[0], acc[i][1] + bv[1]);
      pv.y = pack2(acc[i][2] + bv[2], acc[i][3] + bv[3]);
      pv.z = pack2(acc[i][4] + bv[4], acc[i][5] + bv[5]);
      pv.w = pack2(acc[i][6] + bv[6], acc[i][7] + bv[7]);
      *(uint4*)(out + (size_t)r * 64 + cg * 8) = pv;
    }
  }
}

// ---------------- edge GEMM + fused f_out epilogue + attention logit (no atomics) --------
template <int K, bool STORE, bool ABF>
__global__ __launch_bounds__(256, 2) void gemm_fout_kernel(
    const void* __restrict__ Ap, const float* __restrict__ W, const float* __restrict__ bias,
    const ush* __restrict__ hs, const ush* __restrict__ hd, const int* __restrict__ src,
    const int* __restrict__ dst, const float* __restrict__ attn, ush* __restrict__ fstore,
    float* __restrict__ logit) {
  __shared__ float sA[128][K + 1];
  __shared__ float sW[K][64];
  int t = threadIdx.x;
  int r0 = blockIdx.x * 128;
  for (int i = t; i < K * 16; i += 256) ((float4*)sW)[i] = ((const float4*)W)[i];
  if (ABF) {
    const ush* A = (const ush*)Ap;
    for (int i = t; i < 128 * (K / 8); i += 256) {
      int rr = i / (K / 8), cc = i % (K / 8);
      uint4 v = (r0 + rr < NE) ? ((const uint4*)(A + (size_t)(r0 + rr) * K))[cc]
                               : make_uint4(0, 0, 0, 0);
      float* dp = &sA[rr][cc * 8];
      dp[0] = bf2f(v.x & 0xffff); dp[1] = bf2f(v.x >> 16);
      dp[2] = bf2f(v.y & 0xffff); dp[3] = bf2f(v.y >> 16);
      dp[4] = bf2f(v.z & 0xffff); dp[5] = bf2f(v.z >> 16);
      dp[6] = bf2f(v.w & 0xffff); dp[7] = bf2f(v.w >> 16);
    }
  } else {
    const float* A = (const float*)Ap;
    for (int i = t; i < 128 * (K / 4); i += 256) {
      int rr = i / (K / 4), cc = i % (K / 4);
      float4 v = (r0 + rr < NE) ? ((const float4*)(A + (size_t)(r0 + rr) * K))[cc]
                                : make_float4(0.f, 0.f, 0.f, 0.f);
      sA[rr][cc * 4 + 0] = v.x;
      sA[rr][cc * 4 + 1] = v.y;
      sA[rr][cc * 4 + 2] = v.z;
      sA[rr][cc * 4 + 3] = v.w;
    }
  }
  __syncthreads();
  int rg = t >> 3, cg = t & 7;
  float acc[4][8];
#pragma unroll
  for (int i = 0; i < 4; ++i)
#pragma unroll
    for (int j = 0; j < 8; ++j) acc[i][j] = 0.f;
#pragma unroll 8
  for (int k = 0; k < K; ++k) {
    float a0 = sA[rg * 4 + 0][k], a1 = sA[rg * 4 + 1][k];
    float a2 = sA[rg * 4 + 2][k], a3 = sA[rg * 4 + 3][k];
    float4 wA = *(const float4*)&sW[k][cg * 8];
    float4 wB = *(const float4*)&sW[k][cg * 8 + 4];
#pragma unroll
    for (int i = 0; i < 4; ++i) {
      float a = i == 0 ? a0 : i == 1 ? a1 : i == 2 ? a2 : a3;
      acc[i][0] = fmaf(a, wA.x, acc[i][0]); acc[i][1] = fmaf(a, wA.y, acc[i][1]);
      acc[i][2] = fmaf(a, wA.z, acc[i][2]); acc[i][3] = fmaf(a, wA.w, acc[i][3]);
      acc[i][4] = fmaf(a, wB.x, acc[i][4]); acc[i][5] = fmaf(a, wB.y, acc[i][5]);
      acc[i][6] = fmaf(a, wB.z, acc[i][6]); acc[i][7] = fmaf(a, wB.w, acc[i][7]);
    }
  }
  float bv[8], av[8];
#pragma unroll
  for (int j = 0; j < 8; ++j) {
    bv[j] = bias[cg * 8 + j];
    av[j] = attn[cg * 8 + j];
  }
#pragma unroll
  for (int i = 0; i < 4; ++i) {
    int r = r0 + rg * 4 + i;
    if (r < NE) {
      int s = src[r], d = dst[r];
      uint4 hv = *(const uint4*)(hs + (size_t)s * 64 + cg * 8);
      uint4 dv = *(const uint4*)(hd + (size_t)d * 64 + cg * 8);
      float fo[8];
      fo[0] = acc[i][0] + bf2f(hv.x & 0xffff) + bf2f(dv.x & 0xffff) + bv[0];
      fo[1] = acc[i][1] + bf2f(hv.x >> 16)    + bf2f(dv.x >> 16)    + bv[1];
      fo[2] = acc[i][2] + bf2f(hv.y & 0xffff) + bf2f(dv.y & 0xffff) + bv[2];
      fo[3] = acc[i][3] + bf2f(hv.y >> 16)    + bf2f(dv.y >> 16)    + bv[3];
      fo[4] = acc[i][4] + bf2f(hv.z & 0xffff) + bf2f(dv.z & 0xffff) + bv[4];
      fo[5] = acc[i][5] + bf2f(hv.z >> 16)    + bf2f(dv.z >> 16)    + bv[5];
      fo[6] = acc[i][6] + bf2f(hv.w & 0xffff) + bf2f(dv.w & 0xffff) + bv[6];
      fo[7] = acc[i][7] + bf2f(hv.w >> 16)    + bf2f(dv.w >> 16)    + bv[7];
      float p = 0.f;
#pragma unroll
      for (int j = 0; j < 8; ++j) {
        fo[j] = fo[j] >= 0.f ? fo[j] : 0.01f * fo[j];  // LeakyReLU
        p = fmaf(fo[j], av[j], p);
      }
      if (STORE) {
        uint4 pv;
        pv.x = pack2(fo[0], fo[1]);
        pv.y = pack2(fo[2], fo[3]);
        pv.z = pack2(fo[4], fo[5]);
        pv.w = pack2(fo[6], fo[7]);
        *(uint4*)(fstore + (size_t)r * 64 + cg * 8) = pv;
      }
      p += __shfl_xor(p, 1, 64);
      p += __shfl_xor(p, 2, 64);
      p += __shfl_xor(p, 4, 64);
      if (cg == 0) logit[r] = p;
    }
  }
}

// ---------------- EGAT: gather-aggregate with fused per-node softmax (2-way ILP) ---------
__global__ void agg_gather_kernel(const ush* __restrict__ hn, const float* __restrict__ logit,
                                  const int* __restrict__ rowptr, const int* __restrict__ deg,
                                  const int* __restrict__ src_s, const int* __restrict__ eid_s,
                                  float* __restrict__ hnew) {
  int wave = (blockIdx.x * blockDim.x + threadIdx.x) >> 6;
  int lane = threadIdx.x & 63;
  if (wave >= NN) return;
  int n = wave, d = deg[n], r0 = rowptr[n];
  if (d == 0) {
    hnew[(size_t)n * 64 + lane] = 0.f;
    return;
  }
  float m = -3.0e38f;
  for (int j = 0; j < d; ++j) m = fmaxf(m, logit[eid_s[r0 + j]]);
  float sum0 = 0.f, acc0 = 0.f, sum1 = 0.f, acc1 = 0.f;
  int j = 0;
  for (; j + 1 < d; j += 2) {
    int jj0 = r0 + j, jj1 = r0 + j + 1;
    int s0 = src_s[jj0], s1 = src_s[jj1];
    float w0 = __expf(logit[eid_s[jj0]] - m);
    float w1 = __expf(logit[eid_s[jj1]] - m);
    float v0 = bf2f(hn[(size_t)s0 * 64 + lane]);
    float v1 = bf2f(hn[(size_t)s1 * 64 + lane]);
    sum0 += w0; acc0 = fmaf(w0, v0, acc0);
    sum1 += w1; acc1 = fmaf(w1, v1, acc1);
  }
  if (j < d) {
    int jj = r0 + j;
    float w = __expf(logit[eid_s[jj]] - m);
    sum0 += w;
    acc0 = fmaf(w, bf2f(hn[(size_t)src_s[jj] * 64 + lane]), acc0);
  }
  hnew[(size_t)n * 64 + lane] = (acc0 + acc1) / (sum0 + sum1);
}

// ---------------- NNConv stage 1: z = face @ nn_w (bf16 out), q = face @ nn_b ------------
#define ZCHUNK 128
__global__ void zq_kernel(const float* __restrict__ face, const float* __restrict__ nn_w,
                          const float* __restrict__ nn_b, ush* __restrict__ z,
                          float* __restrict__ q) {
  __shared__ float s_x[ZCHUNK * 32];
  int tid = threadIdx.x;
  int c = blockIdx.y * 256 + tid;  // 0..767, active < 544
  float w[32];
#pragma unroll
  for (int i = 0; i < 32; ++i) w[i] = 0.f;
  if (c < 512) {
    int o = c >> 4, k = c & 15;
#pragma unroll
    for (int i = 0; i < 32; ++i) w[i] = nn_w[(size_t)k * 1024 + i * 32 + o];
  } else if (c < 544) {
    int o = c - 512;
#pragma unroll
    for (int i = 0; i < 32; ++i) w[i] = nn_b[(size_t)i * 32 + o];
  }
  int nbase = blockIdx.x * ZCHUNK;
  int ncnt = min(ZCHUNK, NN - nbase);
  for (int j = tid; j < ncnt * 32; j += 256) s_x[j] = face[(size_t)nbase * 32 + j];
  __syncthreads();
  if (c >= 544) return;
  for (int nl = 0; nl < ncnt; ++nl) {
    const float4* xr = (const float4*)(s_x + nl * 32);
    float acc = 0.f;
#pragma unroll
    for (int j = 0; j < 8; ++j) {
      float4 xv = xr[j];
      acc = fmaf(xv.x, w[j * 4 + 0], acc);
      acc = fmaf(xv.y, w[j * 4 + 1], acc);
      acc = fmaf(xv.z, w[j * 4 + 2], acc);
      acc = fmaf(xv.w, w[j * 4 + 3], acc);
    }
    if (c < 512) z[(size_t)(nbase + nl) * 512 + c] = f2bf(acc);
    else q[(size_t)(nbase + nl) * 32 + (c - 512)] = acc;
  }
}

// ---------------- NNConv pass A (per SRC node): medge[j] = q[s] + ef[e]·z[s] -------------
// z row read ONCE per src node (coalesced); medge written densely in src-order (streaming).
__global__ void nnconv_src_kernel(const ush* __restrict__ z, const float* __restrict__ q,
                                  const float* __restrict__ ef, const int* __restrict__ rowptr_s,
                                  const int* __restrict__ deg_s, const int* __restrict__ eid_ss,
                                  ush* __restrict__ medge) {
  int wave = (blockIdx.x * blockDim.x + threadIdx.x) >> 6;
  int lane = threadIdx.x & 63;
  if (wave >= NN) return;
  int s = wave, d = deg_s[s], r0 = rowptr_s[s];
  if (d == 0) return;
  int o = lane >> 1, half = lane & 1;
  // this lane's 8 z values: k = half*8 .. half*8+7 of output column o
  uint4 zv = *(const uint4*)(z + (size_t)s * 512 + lane * 8);
  float zr[8];
  zr[0] = bf2f(zv.x & 0xffff); zr[1] = bf2f(zv.x >> 16);
  zr[2] = bf2f(zv.y & 0xffff); zr[3] = bf2f(zv.y >> 16);
  zr[4] = bf2f(zv.z & 0xffff); zr[5] = bf2f(zv.z >> 16);
  zr[6] = bf2f(zv.w & 0xffff); zr[7] = bf2f(zv.w >> 16);
  float qv = q[(size_t)s * 32 + o];
  for (int j = 0; j < d; ++j) {
    int jj = r0 + j;
    int e = eid_ss[jj];
    const float4* ep = (const float4*)(ef + (size_t)e * 16 + half * 8);
    float4 e0 = ep[0], e1 = ep[1];
    float acc = e0.x * zr[0];
    acc = fmaf(e0.y, zr[1], acc);
    acc = fmaf(e0.z, zr[2], acc);
    acc = fmaf(e0.w, zr[3], acc);
    acc = fmaf(e1.x, zr[4], acc);
    acc = fmaf(e1.y, zr[5], acc);
    acc = fmaf(e1.z, zr[6], acc);
    acc = fmaf(e1.w, zr[7], acc);
    acc += __shfl_xor(acc, 1, 64);  // combine k-halves
    if (half == 0) medge[(size_t)jj * 32 + o] = f2bf(acc + qv);
  }
}

// ---------------- NNConv pass B (per DST node): sArr[n] = sum medge over in-edges --------
// half-wave per node (lane = (node parity, o)); medge rows gathered via pos_s.
__global__ void nnconv_dst_kernel(const ush* __restrict__ medge, const int* __restrict__ rowptr,
                                  const int* __restrict__ deg, const int* __restrict__ eid_s,
                                  const int* __restrict__ pos_s, float* __restrict__ sArr) {
  int hw = (blockIdx.x * blockDim.x + threadIdx.x) >> 5;  // half-wave index = node
  int o = threadIdx.x & 31;
  if (hw >= NN) return;
  int n = hw, d = deg[n], r0 = rowptr[n];
  float acc = 0.f;
  for (int j = 0; j < d; ++j) {
    int e = eid_s[r0 + j];
    int pp = pos_s[e];
    acc += bf2f(medge[(size_t)pp * 32 + o]);
  }
  sArr[(size_t)n * 32 + o] = acc;
}

// ---------------- combine node_features + gate logit (fused; wave per node) --------------
__global__ void combine_gate_kernel(const float* __restrict__ hfin, const float* __restrict__ sArr,
                                    const int* __restrict__ deg, const float* __restrict__ nn_bias,
                                    const float* __restrict__ gate_w, const float* __restrict__ gate_b,
                                    float* __restrict__ out, float* __restrict__ g) {
  int wave = (blockIdx.x * blockDim.x + threadIdx.x) >> 6;
  int lane = threadIdx.x & 63;
  if (wave >= NN) return;
  int n = wave;
  float v0 = hfin[(size_t)n * 64 + lane];
  int c1 = lane + 64;
  float v1 = (c1 < 96)
                 ? sArr[(size_t)n * 32 + (c1 - 64)] / fmaxf((float)deg[n], 1.0f) + nn_bias[c1 - 64]
                 : 0.f;
  out[(size_t)n * 128 + lane] = v0;
  out[(size_t)n * 128 + c1] = v1;
  float p = v0 * gate_w[lane] + ((c1 < 96) ? v1 * gate_w[c1] : 0.f);
#pragma unroll
  for (int off = 32; off; off >>= 1) p += __shfl_xor(p, off, 64);
  if (lane == 0) g[n] = p + gate_b[0];
}

// ---------------- max over g (block-reduced, 1 atomic per block) ----------------
__global__ void gate_max_kernel(const float* __restrict__ g, unsigned* __restrict__ gmax) {
  int tid = blockIdx.x * blockDim.x + threadIdx.x;
  int stride = gridDim.x * blockDim.x;
  float v = -3.0e38f;
  for (int n = tid; n < NN; n += stride) v = fmaxf(v, g[n]);
#pragma unroll
  for (int off = 32; off; off >>= 1) v = fmaxf(v, __shfl_xor(v, off, 64));
  __shared__ float sm[4];
  int lane = threadIdx.x & 63, wid = threadIdx.x >> 6;
  if (lane == 0) sm[wid] = v;
  __syncthreads();
  if (threadIdx.x == 0) {
    float m = fmaxf(fmaxf(sm[0], sm[1]), fmaxf(sm[2], sm[3]));
    atomicMax(gmax, ord_enc(m));
  }
}

// ---------------- pooling: exp + weighted accumulate (fused) ----------------
__global__ void pool_exp_kernel(const float* __restrict__ nf, const float* __restrict__ g,
                                const unsigned* __restrict__ gmax, float* __restrict__ gacc,
                                float* __restrict__ gsum) {
  int o = threadIdx.x;  // blockDim = 128
  float m = ord_dec(*gmax);
  float acc = 0.f, ws = 0.f;
  for (int n = blockIdx.x; n < NN; n += gridDim.x) {
    float w = __expf(g[n] - m);
    ws += w;
    acc += w * nf[(size_t)n * 128 + o];
  }
  atomicAdd(gacc + o, acc);
  if (o == 0) atomicAdd(gsum, ws);
}

__global__ void finalize_kernel(const float* __restrict__ gacc, const float* __restrict__ gsum,
                                float* __restrict__ out) {
  int o = threadIdx.x;
  if (o < 128) out[(size_t)NN * 128 + o] = gacc[o] / gsum[0];
}

extern "C" void kernel_launch(void* const* d_in, const int* in_sizes, int n_in,
                              void* d_out, int out_size, void* d_ws, size_t ws_size,
                              hipStream_t stream) {
  const float* face    = (const float*)d_in[0];
  const float* ef      = (const float*)d_in[1];
  const float* fp_w    = (const float*)d_in[2];
  const float* fp_b    = (const float*)d_in[3];
  const float* ep_w    = (const float*)d_in[4];
  const float* ep_b    = (const float*)d_in[5];
  const float* nn_w    = (const float*)d_in[6];
  const float* nn_b    = (const float*)d_in[7];
  const float* nn_bias = (const float*)d_in[8];
  const float* gate_w  = (const float*)d_in[9];
  const float* gate_b  = (const float*)d_in[10];
  const int*   src     = (const int*)d_in[11];
  const int*   dst     = (const int*)d_in[12];
  const float* e1_attn = (const float*)d_in[17];
  const float* e2_ni   = (const float*)d_in[19];
  const float* e2_nj   = (const float*)d_in[20];
  const float* e2_fij  = (const float*)d_in[21];
  const float* e2_node = (const float*)d_in[22];
  const float* e2_attn = (const float*)d_in[23];
  const float* e2_bias = (const float*)d_in[24];
  float* out = (float*)d_out;

  char* p = (char*)d_ws;
  auto alloc = [&](size_t nfloats) {
    float* r = (float*)p;
    p += ((nfloats * 4 + 255) / 256) * 256;
    return r;
  };
  float* h0 = alloc((size_t)NN * 64);   // layer-2 output
  float* h1 = alloc((size_t)NN * 64);   // layer-1 output; q aliases after EGAT
  char* regionC = p;                    // hs16|hd16|hn16|f116 = 61.4 MB, dead after EGAT
  ush* hs16 = (ush*)alloc((size_t)NN * 32);   // NN*64 bf16
  ush* hd16 = (ush*)alloc((size_t)NN * 32);
  ush* hn16 = (ush*)alloc((size_t)NN * 32);
  ush* f116 = (ush*)alloc((size_t)NE * 32);   // NE*64 bf16
  float* logit = alloc(NE);
  float* sArr  = alloc((size_t)NN * 32);
  float* g     = alloc(NN);
  float* gacc  = alloc(128);
  float* gsum  = alloc(1);
  unsigned* gmax = (unsigned*)alloc(1);
  float* fold  = alloc(7424);
  // dst-CSR
  int* deg    = (int*)alloc(NN);
  int* rowptr = (int*)alloc(NN);
  int* cursor = (int*)alloc(NN);
  int* partial = (int*)alloc(256);
  int* src_s  = (int*)alloc(NE);
  int* eid_s  = (int*)alloc(NE);
  // src-CSR
  int* deg_s    = (int*)alloc(NN);
  int* rowptr_s = (int*)alloc(NN);
  int* cursor_s = (int*)alloc(NN);
  int* partial2 = (int*)alloc(256);
  int* eid_ss   = (int*)alloc(NE);
  int* pos_s    = (int*)alloc(NE);
  ush* medge    = (ush*)alloc((size_t)NE * 16);  // NE*32 bf16
  ush* z16 = (ush*)regionC;             // NN*512 bf16 = 61.44 MB == regionC exactly
  float* q = h1;                        // NN*32 <= h1's NN*64, h1 dead post-EGAT

  const float* Wf1  = fold;
  const float* b1f  = fold + 1024;
  const float* Wni1 = fold + 1088;
  const float* Wnj1 = fold + 3136;
  const float* Wno1 = fold + 5184;
  const float* bni1 = fold + 7232;
  const float* bnj1 = fold + 7296;
  const float* bno1 = fold + 7360;

  const int B = 256;
  const int NGB = cdiv(NN, 128);
  const int EGB = cdiv(NE, 128);
  const int NB256 = cdiv(NN, 256);

  // ---- CSR builds (dst- and src-sorted) ----
  hipMemsetAsync(deg, 0, NN * 4, stream);
  hipMemsetAsync(deg_s, 0, NN * 4, stream);
  deg_kernel<<<cdiv(NE, B), B, 0, stream>>>(dst, deg);
  deg_kernel<<<cdiv(NE, B), B, 0, stream>>>(src, deg_s);
  scan1_kernel<<<NB256, 256, 0, stream>>>(deg, rowptr, partial);
  scan2_kernel<<<1, 256, 0, stream>>>(partial, NB256);
  scan3_kernel<<<NB256, 256, 0, stream>>>(rowptr, partial, cursor);
  scatter_dst_kernel<<<cdiv(NE, B), B, 0, stream>>>(src, dst, cursor, src_s, eid_s);
  scan1_kernel<<<NB256, 256, 0, stream>>>(deg_s, rowptr_s, partial2);
  scan2_kernel<<<1, 256, 0, stream>>>(partial2, NB256);
  scan3_kernel<<<NB256, 256, 0, stream>>>(rowptr_s, partial2, cursor_s);
  scatter_src_kernel<<<cdiv(NE, B), B, 0, stream>>>(src, cursor_s, eid_ss, pos_s);

  // folded weights (tiny)
  fold_kernel<<<29, B, 0, stream>>>(fp_w, fp_b, ep_w, ep_b,
                                    (const float*)d_in[15], (const float*)d_in[18],
                                    (const float*)d_in[13], (const float*)d_in[14],
                                    (const float*)d_in[16], fold);

  // ---- EGAT layer 1 (face-level folds: h0/f0 never materialized) ----
  gemm3_kernel<32, true><<<dim3(NGB, 3), B, 0, stream>>>(face, Wni1, Wnj1, Wno1, bni1, bnj1,
                                                         bno1, hs16, hd16, hn16, NN);
  gemm_fout_kernel<16, true, false><<<EGB, B, 0, stream>>>(ef, Wf1, b1f, hs16, hd16, src, dst,
                                                           e1_attn, f116, logit);
  agg_gather_kernel<<<cdiv(NN * 64, B), B, 0, stream>>>(hn16, logit, rowptr, deg, src_s,
                                                        eid_s, h1);

  // ---- EGAT layer 2 ----
  gemm3_kernel<64, false><<<dim3(NGB, 3), B, 0, stream>>>(h1, e2_ni, e2_nj, e2_node, nullptr,
                                                          nullptr, nullptr, hs16, hd16, hn16, NN);
  gemm_fout_kernel<64, false, true><<<EGB, B, 0, stream>>>(f116, e2_fij, e2_bias, hs16, hd16,
                                                           src, dst, e2_attn, nullptr, logit);
  agg_gather_kernel<<<cdiv(NN * 64, B), B, 0, stream>>>(hn16, logit, rowptr, deg, src_s,
                                                        eid_s, h0);

  // ---- NNConv (z16/q alias dead EGAT buffers — must run after EGAT) ----
  {
    dim3 zg(cdiv(NN, ZCHUNK), 3);
    zq_kernel<<<zg, B, 0, stream>>>(face, nn_w, nn_b, z16, q);
  }
  nnconv_src_kernel<<<cdiv(NN * 64, B), B, 0, stream>>>(z16, q, ef, rowptr_s, deg_s, eid_ss,
                                                        medge);
  nnconv_dst_kernel<<<cdiv(NN * 32, B), B, 0, stream>>>(medge, rowptr, deg, eid_s, pos_s, sArr);

  // ---- combine node features + gate logits ----
  hipMemsetAsync(gacc, 0, 128 * 4, stream);
  hipMemsetAsync(gsum, 0, 4, stream);
  hipMemsetAsync(gmax, 0, 4, stream);
  combine_gate_kernel<<<cdiv(NN * 64, B), B, 0, stream>>>(h0, sArr, deg, nn_bias, gate_w,
                                                          gate_b, out, g);
  gate_max_kernel<<<128, B, 0, stream>>>(g, gmax);
  pool_exp_kernel<<<512, 128, 0, stream>>>(out, g, gmax, gacc, gsum);
  finalize_kernel<<<1, 128, 0, stream>>>(gacc, gsum, out);
}

// Round 10
// 426.272 us; speedup vs baseline: 1.1765x; 1.1765x over previous
//
#include <hip/hip_runtime.h>

#define NN 60000
#define NE 300000
typedef unsigned short ush;

static inline int cdiv(int a, int b) { return (a + b - 1) / b; }

__device__ inline unsigned ord_enc(float x) {
  unsigned u = __float_as_uint(x);
  return (u & 0x80000000u) ? ~u : (u | 0x80000000u);
}
__device__ inline float ord_dec(unsigned u) {
  return __uint_as_float((u & 0x80000000u) ? (u & 0x7fffffffu) : ~u);
}
__device__ inline float bf2f(unsigned u16) { return __uint_as_float(u16 << 16); }
__device__ inline ush f2bf(float x) {
  unsigned u = __float_as_uint(x);
  return (ush)((u + 0x7FFFu + ((u >> 16) & 1u)) >> 16);
}
__device__ inline unsigned pack2(float lo, float hi) {
  return ((unsigned)f2bf(hi) << 16) | (unsigned)f2bf(lo);
}

// ================= CSR build (dst-sorted) =================
__global__ void deg_kernel(const int* __restrict__ key, int* __restrict__ deg) {
  int e = blockIdx.x * blockDim.x + threadIdx.x;
  if (e < NE) atomicAdd(deg + key[e], 1);
}

__global__ void scan1_kernel(const int* __restrict__ deg, int* __restrict__ rowptr,
                             int* __restrict__ partial) {
  __shared__ int s[256];
  int i = blockIdx.x * 256 + threadIdx.x;
  int v = (i < NN) ? deg[i] : 0;
  s[threadIdx.x] = v;
  __syncthreads();
  for (int off = 1; off < 256; off <<= 1) {
    int t = (threadIdx.x >= off) ? s[threadIdx.x - off] : 0;
    __syncthreads();
    s[threadIdx.x] += t;
    __syncthreads();
  }
  if (i < NN) rowptr[i] = s[threadIdx.x] - v;
  if (threadIdx.x == 255) partial[blockIdx.x] = s[255];
}

__global__ void scan2_kernel(int* __restrict__ partial, int nb) {
  __shared__ int s[256];
  int v = (threadIdx.x < nb) ? partial[threadIdx.x] : 0;
  s[threadIdx.x] = v;
  __syncthreads();
  for (int off = 1; off < 256; off <<= 1) {
    int t = (threadIdx.x >= off) ? s[threadIdx.x - off] : 0;
    __syncthreads();
    s[threadIdx.x] += t;
    __syncthreads();
  }
  if (threadIdx.x < nb) partial[threadIdx.x] = s[threadIdx.x] - v;
}

__global__ void scan3_kernel(int* __restrict__ rowptr, const int* __restrict__ partial,
                             int* __restrict__ cursor) {
  int i = blockIdx.x * 256 + threadIdx.x;
  if (i < NN) {
    int r = rowptr[i] + partial[blockIdx.x];
    rowptr[i] = r;
    cursor[i] = r;
  }
}

__global__ void scatter_dst_kernel(const int* __restrict__ src, const int* __restrict__ dst,
                                   int* __restrict__ cursor, int* __restrict__ src_s,
                                   int* __restrict__ eid_s) {
  int e = blockIdx.x * blockDim.x + threadIdx.x;
  if (e >= NE) return;
  int j = atomicAdd(cursor + dst[e], 1);
  src_s[j] = src[e];
  eid_s[j] = e;
}

// ---------------- fold: precompute folded weight products (7424 dots of length 64) -------
__global__ void fold_kernel(const float* __restrict__ fp_w, const float* __restrict__ fp_b,
                            const float* __restrict__ ep_w, const float* __restrict__ ep_b,
                            const float* __restrict__ fij, const float* __restrict__ ebias,
                            const float* __restrict__ ni, const float* __restrict__ nj,
                            const float* __restrict__ node, float* __restrict__ fold) {
  int t = blockIdx.x * blockDim.x + threadIdx.x;
  if (t >= 7424) return;
  int o = t & 63;
  const float* A;
  const float* B;
  float init = 0.f;
  if (t < 1024)      { A = ep_w + (size_t)(t >> 6) * 64; B = fij + o; }
  else if (t < 1088) { A = ep_b; B = fij + o; init = ebias[o]; }
  else if (t < 3136) { A = fp_w + (size_t)((t - 1088) >> 6) * 64; B = ni + o; }
  else if (t < 5184) { A = fp_w + (size_t)((t - 3136) >> 6) * 64; B = nj + o; }
  else if (t < 7232) { A = fp_w + (size_t)((t - 5184) >> 6) * 64; B = node + o; }
  else if (t < 7296) { A = fp_b; B = ni + o; }
  else if (t < 7360) { A = fp_b; B = nj + o; }
  else               { A = fp_b; B = node + o; }
  float a = init;
  for (int i = 0; i < 64; ++i) a = fmaf(A[i], B[(size_t)i * 64], a);
  fold[t] = a;
}

// ---------------- transpose nn_w/nn_b into W2[32][576]: W2[i][o*16+k]=nn_w[k][i][o] ------
__global__ void nnwt_kernel(const float* __restrict__ nn_w, const float* __restrict__ nn_b,
                            float* __restrict__ W2) {
  int t = blockIdx.x * blockDim.x + threadIdx.x;
  if (t >= 32 * 576) return;
  int i = t / 576, c = t % 576;
  float v = 0.f;
  if (c < 512) v = nn_w[(size_t)(c & 15) * 1024 + i * 32 + (c >> 4)];
  else if (c < 544) v = nn_b[i * 32 + (c - 512)];
  W2[t] = v;
}

// ---------------- tiled GEMM (rows x K) @ (K x 64) -> bf16 out; 3 weight sets ------------
template <int K, bool BIAS>
__global__ __launch_bounds__(256, 2) void gemm3_kernel(
    const float* __restrict__ A, const float* __restrict__ W0, const float* __restrict__ W1,
    const float* __restrict__ W2, const float* __restrict__ b0, const float* __restrict__ b1,
    const float* __restrict__ b2, ush* __restrict__ o0, ush* __restrict__ o1,
    ush* __restrict__ o2, int rows) {
  __shared__ float sA[128][K + 1];
  __shared__ float sW[K][64];
  const float* W = blockIdx.y == 0 ? W0 : blockIdx.y == 1 ? W1 : W2;
  const float* bb = blockIdx.y == 0 ? b0 : blockIdx.y == 1 ? b1 : b2;
  ush* out = blockIdx.y == 0 ? o0 : blockIdx.y == 1 ? o1 : o2;
  int t = threadIdx.x;
  int r0 = blockIdx.x * 128;
  for (int i = t; i < K * 16; i += 256) ((float4*)sW)[i] = ((const float4*)W)[i];
  for (int i = t; i < 128 * (K / 4); i += 256) {
    int rr = i / (K / 4), cc = i % (K / 4);
    float4 v = (r0 + rr < rows) ? ((const float4*)(A + (size_t)(r0 + rr) * K))[cc]
                                : make_float4(0.f, 0.f, 0.f, 0.f);
    sA[rr][cc * 4 + 0] = v.x;
    sA[rr][cc * 4 + 1] = v.y;
    sA[rr][cc * 4 + 2] = v.z;
    sA[rr][cc * 4 + 3] = v.w;
  }
  __syncthreads();
  int rg = t >> 3, cg = t & 7;
  float acc[4][8];
#pragma unroll
  for (int i = 0; i < 4; ++i)
#pragma unroll
    for (int j = 0; j < 8; ++j) acc[i][j] = 0.f;
#pragma unroll 8
  for (int k = 0; k < K; ++k) {
    float a0 = sA[rg * 4 + 0][k], a1 = sA[rg * 4 + 1][k];
    float a2 = sA[rg * 4 + 2][k], a3 = sA[rg * 4 + 3][k];
    float4 wA = *(const float4*)&sW[k][cg * 8];
    float4 wB = *(const float4*)&sW[k][cg * 8 + 4];
#pragma unroll
    for (int i = 0; i < 4; ++i) {
      float a = i == 0 ? a0 : i == 1 ? a1 : i == 2 ? a2 : a3;
      acc[i][0] = fmaf(a, wA.x, acc[i][0]); acc[i][1] = fmaf(a, wA.y, acc[i][1]);
      acc[i][2] = fmaf(a, wA.z, acc[i][2]); acc[i][3] = fmaf(a, wA.w, acc[i][3]);
      acc[i][4] = fmaf(a, wB.x, acc[i][4]); acc[i][5] = fmaf(a, wB.y, acc[i][5]);
      acc[i][6] = fmaf(a, wB.z, acc[i][6]); acc[i][7] = fmaf(a, wB.w, acc[i][7]);
    }
  }
  float bv[8];
#pragma unroll
  for (int j = 0; j < 8; ++j) bv[j] = BIAS ? bb[cg * 8 + j] : 0.f;
#pragma unroll
  for (int i = 0; i < 4; ++i) {
    int r = r0 + rg * 4 + i;
    if (r < rows) {
      uint4 pv;
      pv.x = pack2(acc[i][0] + bv[0], acc[i][1] + bv[1]);
      pv.y = pack2(acc[i][2] + bv[2], acc[i][3] + bv[3]);
      pv.z = pack2(acc[i][4] + bv[4], acc[i][5] + bv[5]);
      pv.w = pack2(acc[i][6] + bv[6], acc[i][7] + bv[7]);
      *(uint4*)(out + (size_t)r * 64 + cg * 8) = pv;
    }
  }
}

// ---------------- zq as tiled GEMM: face(NNx32) @ W2(32x576) -> z bf16 | q f32 -----------
__global__ __launch_bounds__(256, 2) void gemm_zq_kernel(
    const float* __restrict__ A, const float* __restrict__ W2, ush* __restrict__ z,
    float* __restrict__ q, int rows) {
  __shared__ float sA[128][33];
  __shared__ float sW[32][64];
  int t = threadIdx.x;
  int r0 = blockIdx.x * 128;
  int c0 = blockIdx.y * 64;
  for (int i = t; i < 32 * 16; i += 256) {
    int ri = i / 16, cc = i % 16;
    float4 v = *(const float4*)(W2 + (size_t)ri * 576 + c0 + cc * 4);
    *(float4*)&sW[ri][cc * 4] = v;
  }
  for (int i = t; i < 128 * 8; i += 256) {
    int rr = i / 8, cc = i % 8;
    float4 v = (r0 + rr < rows) ? ((const float4*)(A + (size_t)(r0 + rr) * 32))[cc]
                                : make_float4(0.f, 0.f, 0.f, 0.f);
    sA[rr][cc * 4 + 0] = v.x;
    sA[rr][cc * 4 + 1] = v.y;
    sA[rr][cc * 4 + 2] = v.z;
    sA[rr][cc * 4 + 3] = v.w;
  }
  __syncthreads();
  int rg = t >> 3, cg = t & 7;
  float acc[4][8];
#pragma unroll
  for (int i = 0; i < 4; ++i)
#pragma unroll
    for (int j = 0; j < 8; ++j) acc[i][j] = 0.f;
#pragma unroll 8
  for (int k = 0; k < 32; ++k) {
    float a0 = sA[rg * 4 + 0][k], a1 = sA[rg * 4 + 1][k];
    float a2 = sA[rg * 4 + 2][k], a3 = sA[rg * 4 + 3][k];
    float4 wA = *(const float4*)&sW[k][cg * 8];
    float4 wB = *(const float4*)&sW[k][cg * 8 + 4];
#pragma unroll
    for (int i = 0; i < 4; ++i) {
      float a = i == 0 ? a0 : i == 1 ? a1 : i == 2 ? a2 : a3;
      acc[i][0] = fmaf(a, wA.x, acc[i][0]); acc[i][1] = fmaf(a, wA.y, acc[i][1]);
      acc[i][2] = fmaf(a, wA.z, acc[i][2]); acc[i][3] = fmaf(a, wA.w, acc[i][3]);
      acc[i][4] = fmaf(a, wB.x, acc[i][4]); acc[i][5] = fmaf(a, wB.y, acc[i][5]);
      acc[i][6] = fmaf(a, wB.z, acc[i][6]); acc[i][7] = fmaf(a, wB.w, acc[i][7]);
    }
  }
#pragma unroll
  for (int i = 0; i < 4; ++i) {
    int r = r0 + rg * 4 + i;
    if (r < rows) {
      if (blockIdx.y < 8) {
        int c = c0 + cg * 8;
        uint4 pv;
        pv.x = pack2(acc[i][0], acc[i][1]);
        pv.y = pack2(acc[i][2], acc[i][3]);
        pv.z = pack2(acc[i][4], acc[i][5]);
        pv.w = pack2(acc[i][6], acc[i][7]);
        *(uint4*)(z + (size_t)r * 512 + c) = pv;
      } else if (cg < 4) {  // cols 512..543 -> q
        float* qp = q + (size_t)r * 32 + cg * 8;
        *(float4*)qp = make_float4(acc[i][0], acc[i][1], acc[i][2], acc[i][3]);
        *(float4*)(qp + 4) = make_float4(acc[i][4], acc[i][5], acc[i][6], acc[i][7]);
      }
    }
  }
}

// ---------------- edge GEMM + fused f_out epilogue + attention logit (no atomics) --------
template <int K, bool STORE, bool ABF>
__global__ __launch_bounds__(256, 2) void gemm_fout_kernel(
    const void* __restrict__ Ap, const float* __restrict__ W, const float* __restrict__ bias,
    const ush* __restrict__ hs, const ush* __restrict__ hd, const int* __restrict__ src,
    const int* __restrict__ dst, const float* __restrict__ attn, ush* __restrict__ fstore,
    float* __restrict__ logit) {
  __shared__ float sA[128][K + 1];
  __shared__ float sW[K][64];
  int t = threadIdx.x;
  int r0 = blockIdx.x * 128;
  for (int i = t; i < K * 16; i += 256) ((float4*)sW)[i] = ((const float4*)W)[i];
  if (ABF) {
    const ush* A = (const ush*)Ap;
    for (int i = t; i < 128 * (K / 8); i += 256) {
      int rr = i / (K / 8), cc = i % (K / 8);
      uint4 v = (r0 + rr < NE) ? ((const uint4*)(A + (size_t)(r0 + rr) * K))[cc]
                               : make_uint4(0, 0, 0, 0);
      float* dp = &sA[rr][cc * 8];
      dp[0] = bf2f(v.x & 0xffff); dp[1] = bf2f(v.x >> 16);
      dp[2] = bf2f(v.y & 0xffff); dp[3] = bf2f(v.y >> 16);
      dp[4] = bf2f(v.z & 0xffff); dp[5] = bf2f(v.z >> 16);
      dp[6] = bf2f(v.w & 0xffff); dp[7] = bf2f(v.w >> 16);
    }
  } else {
    const float* A = (const float*)Ap;
    for (int i = t; i < 128 * (K / 4); i += 256) {
      int rr = i / (K / 4), cc = i % (K / 4);
      float4 v = (r0 + rr < NE) ? ((const float4*)(A + (size_t)(r0 + rr) * K))[cc]
                                : make_float4(0.f, 0.f, 0.f, 0.f);
      sA[rr][cc * 4 + 0] = v.x;
      sA[rr][cc * 4 + 1] = v.y;
      sA[rr][cc * 4 + 2] = v.z;
      sA[rr][cc * 4 + 3] = v.w;
    }
  }
  __syncthreads();
  int rg = t >> 3, cg = t & 7;
  float acc[4][8];
#pragma unroll
  for (int i = 0; i < 4; ++i)
#pragma unroll
    for (int j = 0; j < 8; ++j) acc[i][j] = 0.f;
#pragma unroll 8
  for (int k = 0; k < K; ++k) {
    float a0 = sA[rg * 4 + 0][k], a1 = sA[rg * 4 + 1][k];
    float a2 = sA[rg * 4 + 2][k], a3 = sA[rg * 4 + 3][k];
    float4 wA = *(const float4*)&sW[k][cg * 8];
    float4 wB = *(const float4*)&sW[k][cg * 8 + 4];
#pragma unroll
    for (int i = 0; i < 4; ++i) {
      float a = i == 0 ? a0 : i == 1 ? a1 : i == 2 ? a2 : a3;
      acc[i][0] = fmaf(a, wA.x, acc[i][0]); acc[i][1] = fmaf(a, wA.y, acc[i][1]);
      acc[i][2] = fmaf(a, wA.z, acc[i][2]); acc[i][3] = fmaf(a, wA.w, acc[i][3]);
      acc[i][4] = fmaf(a, wB.x, acc[i][4]); acc[i][5] = fmaf(a, wB.y, acc[i][5]);
      acc[i][6] = fmaf(a, wB.z, acc[i][6]); acc[i][7] = fmaf(a, wB.w, acc[i][7]);
    }
  }
  float bv[8], av[8];
#pragma unroll
  for (int j = 0; j < 8; ++j) {
    bv[j] = bias[cg * 8 + j];
    av[j] = attn[cg * 8 + j];
  }
#pragma unroll
  for (int i = 0; i < 4; ++i) {
    int r = r0 + rg * 4 + i;
    if (r < NE) {
      int s = src[r], d = dst[r];
      uint4 hv = *(const uint4*)(hs + (size_t)s * 64 + cg * 8);
      uint4 dv = *(const uint4*)(hd + (size_t)d * 64 + cg * 8);
      float fo[8];
      fo[0] = acc[i][0] + bf2f(hv.x & 0xffff) + bf2f(dv.x & 0xffff) + bv[0];
      fo[1] = acc[i][1] + bf2f(hv.x >> 16)    + bf2f(dv.x >> 16)    + bv[1];
      fo[2] = acc[i][2] + bf2f(hv.y & 0xffff) + bf2f(dv.y & 0xffff) + bv[2];
      fo[3] = acc[i][3] + bf2f(hv.y >> 16)    + bf2f(dv.y >> 16)    + bv[3];
      fo[4] = acc[i][4] + bf2f(hv.z & 0xffff) + bf2f(dv.z & 0xffff) + bv[4];
      fo[5] = acc[i][5] + bf2f(hv.z >> 16)    + bf2f(dv.z >> 16)    + bv[5];
      fo[6] = acc[i][6] + bf2f(hv.w & 0xffff) + bf2f(dv.w & 0xffff) + bv[6];
      fo[7] = acc[i][7] + bf2f(hv.w >> 16)    + bf2f(dv.w >> 16)    + bv[7];
      float p = 0.f;
#pragma unroll
      for (int j = 0; j < 8; ++j) {
        fo[j] = fo[j] >= 0.f ? fo[j] : 0.01f * fo[j];  // LeakyReLU
        p = fmaf(fo[j], av[j], p);
      }
      if (STORE) {
        uint4 pv;
        pv.x = pack2(fo[0], fo[1]);
        pv.y = pack2(fo[2], fo[3]);
        pv.z = pack2(fo[4], fo[5]);
        pv.w = pack2(fo[6], fo[7]);
        *(uint4*)(fstore + (size_t)r * 64 + cg * 8) = pv;
      }
      p += __shfl_xor(p, 1, 64);
      p += __shfl_xor(p, 2, 64);
      p += __shfl_xor(p, 4, 64);
      if (cg == 0) logit[r] = p;
    }
  }
}

// ---------------- EGAT: gather-aggregate with fused per-node softmax (2-way ILP) ---------
__global__ void agg_gather_kernel(const ush* __restrict__ hn, const float* __restrict__ logit,
                                  const int* __restrict__ rowptr, const int* __restrict__ deg,
                                  const int* __restrict__ src_s, const int* __restrict__ eid_s,
                                  float* __restrict__ hnew) {
  int wave = (blockIdx.x * blockDim.x + threadIdx.x) >> 6;
  int lane = threadIdx.x & 63;
  if (wave >= NN) return;
  int n = wave, d = deg[n], r0 = rowptr[n];
  if (d == 0) {
    hnew[(size_t)n * 64 + lane] = 0.f;
    return;
  }
  float m = -3.0e38f;
  for (int j = 0; j < d; ++j) m = fmaxf(m, logit[eid_s[r0 + j]]);
  float sum0 = 0.f, acc0 = 0.f, sum1 = 0.f, acc1 = 0.f;
  int j = 0;
  for (; j + 1 < d; j += 2) {
    int jj0 = r0 + j, jj1 = r0 + j + 1;
    int s0 = src_s[jj0], s1 = src_s[jj1];
    float w0 = __expf(logit[eid_s[jj0]] - m);
    float w1 = __expf(logit[eid_s[jj1]] - m);
    float v0 = bf2f(hn[(size_t)s0 * 64 + lane]);
    float v1 = bf2f(hn[(size_t)s1 * 64 + lane]);
    sum0 += w0; acc0 = fmaf(w0, v0, acc0);
    sum1 += w1; acc1 = fmaf(w1, v1, acc1);
  }
  if (j < d) {
    int jj = r0 + j;
    float w = __expf(logit[eid_s[jj]] - m);
    sum0 += w;
    acc0 = fmaf(w, bf2f(hn[(size_t)src_s[jj] * 64 + lane]), acc0);
  }
  hnew[(size_t)n * 64 + lane] = (acc0 + acc1) / (sum0 + sum1);
}

// ---------------- NNConv stage 2 (gather, 2-edge ILP): per dst node ----------------
__global__ void nnconv_gather_kernel(const ush* __restrict__ z, const float* __restrict__ q,
                                     const float* __restrict__ ef, const int* __restrict__ rowptr,
                                     const int* __restrict__ deg, const int* __restrict__ src_s,
                                     const int* __restrict__ eid_s, float* __restrict__ sArr) {
  int wave = (blockIdx.x * blockDim.x + threadIdx.x) >> 6;
  int lane = threadIdx.x & 63;
  if (wave >= NN) return;
  int n = wave, d = deg[n], r0 = rowptr[n];
  int o = lane >> 1, half = lane & 1;
  float acc0 = 0.f, acc1 = 0.f;
  int j = 0;
  for (; j + 1 < d; j += 2) {
    int jj0 = r0 + j, jj1 = r0 + j + 1;
    int s0 = src_s[jj0], e0 = eid_s[jj0];
    int s1 = src_s[jj1], e1 = eid_s[jj1];
    const float4* ep0 = (const float4*)(ef + (size_t)e0 * 16 + half * 8);
    const float4* ep1 = (const float4*)(ef + (size_t)e1 * 16 + half * 8);
    float4 ea0 = ep0[0], eb0 = ep0[1];
    float4 ea1 = ep1[0], eb1 = ep1[1];
    uint4 zv0 = *(const uint4*)(z + (size_t)s0 * 512 + lane * 8);
    uint4 zv1 = *(const uint4*)(z + (size_t)s1 * 512 + lane * 8);
    acc0 = fmaf(ea0.x, bf2f(zv0.x & 0xffff), acc0);
    acc0 = fmaf(ea0.y, bf2f(zv0.x >> 16), acc0);
    acc0 = fmaf(ea0.z, bf2f(zv0.y & 0xffff), acc0);
    acc0 = fmaf(ea0.w, bf2f(zv0.y >> 16), acc0);
    acc0 = fmaf(eb0.x, bf2f(zv0.z & 0xffff), acc0);
    acc0 = fmaf(eb0.y, bf2f(zv0.z >> 16), acc0);
    acc0 = fmaf(eb0.z, bf2f(zv0.w & 0xffff), acc0);
    acc0 = fmaf(eb0.w, bf2f(zv0.w >> 16), acc0);
    acc1 = fmaf(ea1.x, bf2f(zv1.x & 0xffff), acc1);
    acc1 = fmaf(ea1.y, bf2f(zv1.x >> 16), acc1);
    acc1 = fmaf(ea1.z, bf2f(zv1.y & 0xffff), acc1);
    acc1 = fmaf(ea1.w, bf2f(zv1.y >> 16), acc1);
    acc1 = fmaf(eb1.x, bf2f(zv1.z & 0xffff), acc1);
    acc1 = fmaf(eb1.y, bf2f(zv1.z >> 16), acc1);
    acc1 = fmaf(eb1.z, bf2f(zv1.w & 0xffff), acc1);
    acc1 = fmaf(eb1.w, bf2f(zv1.w >> 16), acc1);
    if (half == 0) {
      acc0 += q[(size_t)s0 * 32 + o];
      acc1 += q[(size_t)s1 * 32 + o];
    }
  }
  if (j < d) {
    int jj = r0 + j;
    int s = src_s[jj], e = eid_s[jj];
    const float4* ep = (const float4*)(ef + (size_t)e * 16 + half * 8);
    float4 ea = ep[0], eb = ep[1];
    uint4 zv = *(const uint4*)(z + (size_t)s * 512 + lane * 8);
    acc0 = fmaf(ea.x, bf2f(zv.x & 0xffff), acc0);
    acc0 = fmaf(ea.y, bf2f(zv.x >> 16), acc0);
    acc0 = fmaf(ea.z, bf2f(zv.y & 0xffff), acc0);
    acc0 = fmaf(ea.w, bf2f(zv.y >> 16), acc0);
    acc0 = fmaf(eb.x, bf2f(zv.z & 0xffff), acc0);
    acc0 = fmaf(eb.y, bf2f(zv.z >> 16), acc0);
    acc0 = fmaf(eb.z, bf2f(zv.w & 0xffff), acc0);
    acc0 = fmaf(eb.w, bf2f(zv.w >> 16), acc0);
    if (half == 0) acc0 += q[(size_t)s * 32 + o];
  }
  float acc = acc0 + acc1;
  acc += __shfl_xor(acc, 1, 64);
  if (half == 0) sArr[(size_t)n * 32 + o] = acc;
}

// ---------------- combine node_features + gate logit (fused; wave per node) --------------
__global__ void combine_gate_kernel(const float* __restrict__ hfin, const float* __restrict__ sArr,
                                    const int* __restrict__ deg, const float* __restrict__ nn_bias,
                                    const float* __restrict__ gate_w, const float* __restrict__ gate_b,
                                    float* __restrict__ out, float* __restrict__ g) {
  int wave = (blockIdx.x * blockDim.x + threadIdx.x) >> 6;
  int lane = threadIdx.x & 63;
  if (wave >= NN) return;
  int n = wave;
  float v0 = hfin[(size_t)n * 64 + lane];
  int c1 = lane + 64;
  float v1 = (c1 < 96)
                 ? sArr[(size_t)n * 32 + (c1 - 64)] / fmaxf((float)deg[n], 1.0f) + nn_bias[c1 - 64]
                 : 0.f;
  out[(size_t)n * 128 + lane] = v0;
  out[(size_t)n * 128 + c1] = v1;
  float p = v0 * gate_w[lane] + ((c1 < 96) ? v1 * gate_w[c1] : 0.f);
#pragma unroll
  for (int off = 32; off; off >>= 1) p += __shfl_xor(p, off, 64);
  if (lane == 0) g[n] = p + gate_b[0];
}

// ---------------- max over g (block-reduced, 1 atomic per block) ----------------
__global__ void gate_max_kernel(const float* __restrict__ g, unsigned* __restrict__ gmax) {
  int tid = blockIdx.x * blockDim.x + threadIdx.x;
  int stride = gridDim.x * blockDim.x;
  float v = -3.0e38f;
  for (int n = tid; n < NN; n += stride) v = fmaxf(v, g[n]);
#pragma unroll
  for (int off = 32; off; off >>= 1) v = fmaxf(v, __shfl_xor(v, off, 64));
  __shared__ float sm[4];
  int lane = threadIdx.x & 63, wid = threadIdx.x >> 6;
  if (lane == 0) sm[wid] = v;
  __syncthreads();
  if (threadIdx.x == 0) {
    float m = fmaxf(fmaxf(sm[0], sm[1]), fmaxf(sm[2], sm[3]));
    atomicMax(gmax, ord_enc(m));
  }
}

// ---------------- pooling: exp + weighted accumulate (fused) ----------------
__global__ void pool_exp_kernel(const float* __restrict__ nf, const float* __restrict__ g,
                                const unsigned* __restrict__ gmax, float* __restrict__ gacc,
                                float* __restrict__ gsum) {
  int o = threadIdx.x;  // blockDim = 128
  float m = ord_dec(*gmax);
  float acc = 0.f, ws = 0.f;
  for (int n = blockIdx.x; n < NN; n += gridDim.x) {
    float w = __expf(g[n] - m);
    ws += w;
    acc += w * nf[(size_t)n * 128 + o];
  }
  atomicAdd(gacc + o, acc);
  if (o == 0) atomicAdd(gsum, ws);
}

__global__ void finalize_kernel(const float* __restrict__ gacc, const float* __restrict__ gsum,
                                float* __restrict__ out) {
  int o = threadIdx.x;
  if (o < 128) out[(size_t)NN * 128 + o] = gacc[o] / gsum[0];
}

extern "C" void kernel_launch(void* const* d_in, const int* in_sizes, int n_in,
                              void* d_out, int out_size, void* d_ws, size_t ws_size,
                              hipStream_t stream) {
  const float* face    = (const float*)d_in[0];
  const float* ef      = (const float*)d_in[1];
  const float* fp_w    = (const float*)d_in[2];
  const float* fp_b    = (const float*)d_in[3];
  const float* ep_w    = (const float*)d_in[4];
  const float* ep_b    = (const float*)d_in[5];
  const float* nn_w    = (const float*)d_in[6];
  const float* nn_b    = (const float*)d_in[7];
  const float* nn_bias = (const float*)d_in[8];
  const float* gate_w  = (const float*)d_in[9];
  const float* gate_b  = (const float*)d_in[10];
  const int*   src     = (const int*)d_in[11];
  const int*   dst     = (const int*)d_in[12];
  const float* e1_attn = (const float*)d_in[17];
  const float* e2_ni   = (const float*)d_in[19];
  const float* e2_nj   = (const float*)d_in[20];
  const float* e2_fij  = (const float*)d_in[21];
  const float* e2_node = (const float*)d_in[22];
  const float* e2_attn = (const float*)d_in[23];
  const float* e2_bias = (const float*)d_in[24];
  float* out = (float*)d_out;

  char* p = (char*)d_ws;
  auto alloc = [&](size_t nfloats) {
    float* r = (float*)p;
    p += ((nfloats * 4 + 255) / 256) * 256;
    return r;
  };
  float* h0 = alloc((size_t)NN * 64);   // layer-2 output
  float* h1 = alloc((size_t)NN * 64);   // layer-1 output; q aliases after EGAT
  char* regionC = p;                    // hs16|hd16|hn16|f116 = 61.4 MB, dead after EGAT
  ush* hs16 = (ush*)alloc((size_t)NN * 32);   // NN*64 bf16
  ush* hd16 = (ush*)alloc((size_t)NN * 32);
  ush* hn16 = (ush*)alloc((size_t)NN * 32);
  ush* f116 = (ush*)alloc((size_t)NE * 32);   // NE*64 bf16
  float* logit = alloc(NE);
  float* sArr  = alloc((size_t)NN * 32);
  float* g     = alloc(NN);
  float* gacc  = alloc(128);
  float* gsum  = alloc(1);
  unsigned* gmax = (unsigned*)alloc(1);
  float* fold  = alloc(7424);
  float* W2    = alloc(32 * 576);
  // dst-CSR
  int* deg    = (int*)alloc(NN);
  int* rowptr = (int*)alloc(NN);
  int* cursor = (int*)alloc(NN);
  int* partial = (int*)alloc(256);
  int* src_s  = (int*)alloc(NE);
  int* eid_s  = (int*)alloc(NE);
  ush* z16 = (ush*)regionC;             // NN*512 bf16 = 61.44 MB == regionC exactly
  float* q = h1;                        // NN*32 <= h1's NN*64, h1 dead post-EGAT

  const float* Wf1  = fold;
  const float* b1f  = fold + 1024;
  const float* Wni1 = fold + 1088;
  const float* Wnj1 = fold + 3136;
  const float* Wno1 = fold + 5184;
  const float* bni1 = fold + 7232;
  const float* bnj1 = fold + 7296;
  const float* bno1 = fold + 7360;

  const int B = 256;
  const int NGB = cdiv(NN, 128);
  const int EGB = cdiv(NE, 128);
  const int NB256 = cdiv(NN, 256);

  // ---- CSR build (dst-sorted) ----
  hipMemsetAsync(deg, 0, NN * 4, stream);
  deg_kernel<<<cdiv(NE, B), B, 0, stream>>>(dst, deg);
  scan1_kernel<<<NB256, 256, 0, stream>>>(deg, rowptr, partial);
  scan2_kernel<<<1, 256, 0, stream>>>(partial, NB256);
  scan3_kernel<<<NB256, 256, 0, stream>>>(rowptr, partial, cursor);
  scatter_dst_kernel<<<cdiv(NE, B), B, 0, stream>>>(src, dst, cursor, src_s, eid_s);

  // folded weights + nn_w transpose (tiny)
  fold_kernel<<<29, B, 0, stream>>>(fp_w, fp_b, ep_w, ep_b,
                                    (const float*)d_in[15], (const float*)d_in[18],
                                    (const float*)d_in[13], (const float*)d_in[14],
                                    (const float*)d_in[16], fold);
  nnwt_kernel<<<72, B, 0, stream>>>(nn_w, nn_b, W2);

  // ---- EGAT layer 1 (face-level folds: h0/f0 never materialized) ----
  gemm3_kernel<32, true><<<dim3(NGB, 3), B, 0, stream>>>(face, Wni1, Wnj1, Wno1, bni1, bnj1,
                                                         bno1, hs16, hd16, hn16, NN);
  gemm_fout_kernel<16, true, false><<<EGB, B, 0, stream>>>(ef, Wf1, b1f, hs16, hd16, src, dst,
                                                           e1_attn, f116, logit);
  agg_gather_kernel<<<cdiv(NN * 64, B), B, 0, stream>>>(hn16, logit, rowptr, deg, src_s,
                                                        eid_s, h1);

  // ---- EGAT layer 2 ----
  gemm3_kernel<64, false><<<dim3(NGB, 3), B, 0, stream>>>(h1, e2_ni, e2_nj, e2_node, nullptr,
                                                          nullptr, nullptr, hs16, hd16, hn16, NN);
  gemm_fout_kernel<64, false, true><<<EGB, B, 0, stream>>>(f116, e2_fij, e2_bias, hs16, hd16,
                                                           src, dst, e2_attn, nullptr, logit);
  agg_gather_kernel<<<cdiv(NN * 64, B), B, 0, stream>>>(hn16, logit, rowptr, deg, src_s,
                                                        eid_s, h0);

  // ---- NNConv (z16/q alias dead EGAT buffers — must run after EGAT) ----
  gemm_zq_kernel<<<dim3(NGB, 9), B, 0, stream>>>(face, W2, z16, q, NN);
  nnconv_gather_kernel<<<cdiv(NN * 64, B), B, 0, stream>>>(z16, q, ef, rowptr, deg, src_s,
                                                           eid_s, sArr);

  // ---- combine node features + gate logits ----
  hipMemsetAsync(gacc, 0, 128 * 4, stream);
  hipMemsetAsync(gsum, 0, 4, stream);
  hipMemsetAsync(gmax, 0, 4, stream);
  combine_gate_kernel<<<cdiv(NN * 64, B), B, 0, stream>>>(h0, sArr, deg, nn_bias, gate_w,
                                                          gate_b, out, g);
  gate_max_kernel<<<128, B, 0, stream>>>(g, gmax);
  pool_exp_kernel<<<512, 128, 0, stream>>>(out, g, gmax, gacc, gsum);
  finalize_kernel<<<1, 128, 0, stream>>>(gacc, gsum, out);
}

// Round 11
// 425.853 us; speedup vs baseline: 1.1776x; 1.0010x over previous
//
#include <hip/hip_runtime.h>

#define NN 60000
#define NE 300000
typedef unsigned short ush;

static inline int cdiv(int a, int b) { return (a + b - 1) / b; }

__device__ inline unsigned ord_enc(float x) {
  unsigned u = __float_as_uint(x);
  return (u & 0x80000000u) ? ~u : (u | 0x80000000u);
}
__device__ inline float ord_dec(unsigned u) {
  return __uint_as_float((u & 0x80000000u) ? (u & 0x7fffffffu) : ~u);
}
__device__ inline float bf2f(unsigned u16) { return __uint_as_float(u16 << 16); }
__device__ inline ush f2bf(float x) {
  unsigned u = __float_as_uint(x);
  return (ush)((u + 0x7FFFu + ((u >> 16) & 1u)) >> 16);
}
__device__ inline unsigned pack2(float lo, float hi) {
  return ((unsigned)f2bf(hi) << 16) | (unsigned)f2bf(lo);
}

// ================= CSR build (dst-sorted) =================
__global__ void deg_kernel(const int* __restrict__ key, int* __restrict__ deg) {
  int e = blockIdx.x * blockDim.x + threadIdx.x;
  if (e < NE) atomicAdd(deg + key[e], 1);
}

__global__ void scan1_kernel(const int* __restrict__ deg, int* __restrict__ rowptr,
                             int* __restrict__ partial) {
  __shared__ int s[256];
  int i = blockIdx.x * 256 + threadIdx.x;
  int v = (i < NN) ? deg[i] : 0;
  s[threadIdx.x] = v;
  __syncthreads();
  for (int off = 1; off < 256; off <<= 1) {
    int t = (threadIdx.x >= off) ? s[threadIdx.x - off] : 0;
    __syncthreads();
    s[threadIdx.x] += t;
    __syncthreads();
  }
  if (i < NN) rowptr[i] = s[threadIdx.x] - v;
  if (threadIdx.x == 255) partial[blockIdx.x] = s[255];
}

__global__ void scan2_kernel(int* __restrict__ partial, int nb) {
  __shared__ int s[256];
  int v = (threadIdx.x < nb) ? partial[threadIdx.x] : 0;
  s[threadIdx.x] = v;
  __syncthreads();
  for (int off = 1; off < 256; off <<= 1) {
    int t = (threadIdx.x >= off) ? s[threadIdx.x - off] : 0;
    __syncthreads();
    s[threadIdx.x] += t;
    __syncthreads();
  }
  if (threadIdx.x < nb) partial[threadIdx.x] = s[threadIdx.x] - v;
}

__global__ void scan3_kernel(int* __restrict__ rowptr, const int* __restrict__ partial,
                             int* __restrict__ cursor) {
  int i = blockIdx.x * 256 + threadIdx.x;
  if (i < NN) {
    int r = rowptr[i] + partial[blockIdx.x];
    rowptr[i] = r;
    cursor[i] = r;
  }
}

__global__ void scatter_dst_kernel(const int* __restrict__ src, const int* __restrict__ dst,
                                   int* __restrict__ cursor, int* __restrict__ src_s,
                                   int* __restrict__ dst_s, int* __restrict__ eid_s) {
  int e = blockIdx.x * blockDim.x + threadIdx.x;
  if (e >= NE) return;
  int d = dst[e];
  int j = atomicAdd(cursor + d, 1);
  src_s[j] = src[e];
  dst_s[j] = d;
  eid_s[j] = e;
}

// permute ef rows into dst-sorted order (sequential write, gathered read)
__global__ void permute_ef_kernel(const float* __restrict__ ef, const int* __restrict__ eid_s,
                                  float* __restrict__ ef_s) {
  int j = blockIdx.x * blockDim.x + threadIdx.x;
  if (j >= NE * 4) return;
  int slot = j >> 2, c = j & 3;
  int e = eid_s[slot];
  ((float4*)ef_s)[(size_t)slot * 4 + c] = ((const float4*)ef)[(size_t)e * 4 + c];
}

// ---------------- fold: precompute folded weight products (7424 dots of length 64) -------
__global__ void fold_kernel(const float* __restrict__ fp_w, const float* __restrict__ fp_b,
                            const float* __restrict__ ep_w, const float* __restrict__ ep_b,
                            const float* __restrict__ fij, const float* __restrict__ ebias,
                            const float* __restrict__ ni, const float* __restrict__ nj,
                            const float* __restrict__ node, float* __restrict__ fold) {
  int t = blockIdx.x * blockDim.x + threadIdx.x;
  if (t >= 7424) return;
  int o = t & 63;
  const float* A;
  const float* B;
  float init = 0.f;
  if (t < 1024)      { A = ep_w + (size_t)(t >> 6) * 64; B = fij + o; }
  else if (t < 1088) { A = ep_b; B = fij + o; init = ebias[o]; }
  else if (t < 3136) { A = fp_w + (size_t)((t - 1088) >> 6) * 64; B = ni + o; }
  else if (t < 5184) { A = fp_w + (size_t)((t - 3136) >> 6) * 64; B = nj + o; }
  else if (t < 7232) { A = fp_w + (size_t)((t - 5184) >> 6) * 64; B = node + o; }
  else if (t < 7296) { A = fp_b; B = ni + o; }
  else if (t < 7360) { A = fp_b; B = nj + o; }
  else               { A = fp_b; B = node + o; }
  float a = init;
  for (int i = 0; i < 64; ++i) a = fmaf(A[i], B[(size_t)i * 64], a);
  fold[t] = a;
}

// ---------------- transpose nn_w/nn_b into W2[32][576] ----------------
__global__ void nnwt_kernel(const float* __restrict__ nn_w, const float* __restrict__ nn_b,
                            float* __restrict__ W2) {
  int t = blockIdx.x * blockDim.x + threadIdx.x;
  if (t >= 32 * 576) return;
  int i = t / 576, c = t % 576;
  float v = 0.f;
  if (c < 512) v = nn_w[(size_t)(c & 15) * 1024 + i * 32 + (c >> 4)];
  else if (c < 544) v = nn_b[i * 32 + (c - 512)];
  W2[t] = v;
}

// ---------------- tiled GEMM (rows x K) @ (K x 64) -> bf16 out; 3 weight sets ------------
template <int K, bool BIAS>
__global__ __launch_bounds__(256, 2) void gemm3_kernel(
    const float* __restrict__ A, const float* __restrict__ W0, const float* __restrict__ W1,
    const float* __restrict__ W2, const float* __restrict__ b0, const float* __restrict__ b1,
    const float* __restrict__ b2, ush* __restrict__ o0, ush* __restrict__ o1,
    ush* __restrict__ o2, int rows) {
  __shared__ float sA[128][K + 1];
  __shared__ float sW[K][64];
  const float* W = blockIdx.y == 0 ? W0 : blockIdx.y == 1 ? W1 : W2;
  const float* bb = blockIdx.y == 0 ? b0 : blockIdx.y == 1 ? b1 : b2;
  ush* out = blockIdx.y == 0 ? o0 : blockIdx.y == 1 ? o1 : o2;
  int t = threadIdx.x;
  int r0 = blockIdx.x * 128;
  for (int i = t; i < K * 16; i += 256) ((float4*)sW)[i] = ((const float4*)W)[i];
  for (int i = t; i < 128 * (K / 4); i += 256) {
    int rr = i / (K / 4), cc = i % (K / 4);
    float4 v = (r0 + rr < rows) ? ((const float4*)(A + (size_t)(r0 + rr) * K))[cc]
                                : make_float4(0.f, 0.f, 0.f, 0.f);
    sA[rr][cc * 4 + 0] = v.x;
    sA[rr][cc * 4 + 1] = v.y;
    sA[rr][cc * 4 + 2] = v.z;
    sA[rr][cc * 4 + 3] = v.w;
  }
  __syncthreads();
  int rg = t >> 3, cg = t & 7;
  float acc[4][8];
#pragma unroll
  for (int i = 0; i < 4; ++i)
#pragma unroll
    for (int j = 0; j < 8; ++j) acc[i][j] = 0.f;
#pragma unroll 8
  for (int k = 0; k < K; ++k) {
    float a0 = sA[rg * 4 + 0][k], a1 = sA[rg * 4 + 1][k];
    float a2 = sA[rg * 4 + 2][k], a3 = sA[rg * 4 + 3][k];
    float4 wA = *(const float4*)&sW[k][cg * 8];
    float4 wB = *(const float4*)&sW[k][cg * 8 + 4];
#pragma unroll
    for (int i = 0; i < 4; ++i) {
      float a = i == 0 ? a0 : i == 1 ? a1 : i == 2 ? a2 : a3;
      acc[i][0] = fmaf(a, wA.x, acc[i][0]); acc[i][1] = fmaf(a, wA.y, acc[i][1]);
      acc[i][2] = fmaf(a, wA.z, acc[i][2]); acc[i][3] = fmaf(a, wA.w, acc[i][3]);
      acc[i][4] = fmaf(a, wB.x, acc[i][4]); acc[i][5] = fmaf(a, wB.y, acc[i][5]);
      acc[i][6] = fmaf(a, wB.z, acc[i][6]); acc[i][7] = fmaf(a, wB.w, acc[i][7]);
    }
  }
  float bv[8];
#pragma unroll
  for (int j = 0; j < 8; ++j) bv[j] = BIAS ? bb[cg * 8 + j] : 0.f;
#pragma unroll
  for (int i = 0; i < 4; ++i) {
    int r = r0 + rg * 4 + i;
    if (r < rows) {
      uint4 pv;
      pv.x = pack2(acc[i][0] + bv[0], acc[i][1] + bv[1]);
      pv.y = pack2(acc[i][2] + bv[2], acc[i][3] + bv[3]);
      pv.z = pack2(acc[i][4] + bv[4], acc[i][5] + bv[5]);
      pv.w = pack2(acc[i][6] + bv[6], acc[i][7] + bv[7]);
      *(uint4*)(out + (size_t)r * 64 + cg * 8) = pv;
    }
  }
}

// ---------------- zq as tiled GEMM: face(NNx32) @ W2(32x576) -> z bf16 | q f32 -----------
__global__ __launch_bounds__(256, 2) void gemm_zq_kernel(
    const float* __restrict__ A, const float* __restrict__ W2, ush* __restrict__ z,
    float* __restrict__ q, int rows) {
  __shared__ float sA[128][33];
  __shared__ float sW[32][64];
  int t = threadIdx.x;
  int r0 = blockIdx.x * 128;
  int c0 = blockIdx.y * 64;
  for (int i = t; i < 32 * 16; i += 256) {
    int ri = i / 16, cc = i % 16;
    float4 v = *(const float4*)(W2 + (size_t)ri * 576 + c0 + cc * 4);
    *(float4*)&sW[ri][cc * 4] = v;
  }
  for (int i = t; i < 128 * 8; i += 256) {
    int rr = i / 8, cc = i % 8;
    float4 v = (r0 + rr < rows) ? ((const float4*)(A + (size_t)(r0 + rr) * 32))[cc]
                                : make_float4(0.f, 0.f, 0.f, 0.f);
    sA[rr][cc * 4 + 0] = v.x;
    sA[rr][cc * 4 + 1] = v.y;
    sA[rr][cc * 4 + 2] = v.z;
    sA[rr][cc * 4 + 3] = v.w;
  }
  __syncthreads();
  int rg = t >> 3, cg = t & 7;
  float acc[4][8];
#pragma unroll
  for (int i = 0; i < 4; ++i)
#pragma unroll
    for (int j = 0; j < 8; ++j) acc[i][j] = 0.f;
#pragma unroll 8
  for (int k = 0; k < 32; ++k) {
    float a0 = sA[rg * 4 + 0][k], a1 = sA[rg * 4 + 1][k];
    float a2 = sA[rg * 4 + 2][k], a3 = sA[rg * 4 + 3][k];
    float4 wA = *(const float4*)&sW[k][cg * 8];
    float4 wB = *(const float4*)&sW[k][cg * 8 + 4];
#pragma unroll
    for (int i = 0; i < 4; ++i) {
      float a = i == 0 ? a0 : i == 1 ? a1 : i == 2 ? a2 : a3;
      acc[i][0] = fmaf(a, wA.x, acc[i][0]); acc[i][1] = fmaf(a, wA.y, acc[i][1]);
      acc[i][2] = fmaf(a, wA.z, acc[i][2]); acc[i][3] = fmaf(a, wA.w, acc[i][3]);
      acc[i][4] = fmaf(a, wB.x, acc[i][4]); acc[i][5] = fmaf(a, wB.y, acc[i][5]);
      acc[i][6] = fmaf(a, wB.z, acc[i][6]); acc[i][7] = fmaf(a, wB.w, acc[i][7]);
    }
  }
#pragma unroll
  for (int i = 0; i < 4; ++i) {
    int r = r0 + rg * 4 + i;
    if (r < rows) {
      if (blockIdx.y < 8) {
        int c = c0 + cg * 8;
        uint4 pv;
        pv.x = pack2(acc[i][0], acc[i][1]);
        pv.y = pack2(acc[i][2], acc[i][3]);
        pv.z = pack2(acc[i][4], acc[i][5]);
        pv.w = pack2(acc[i][6], acc[i][7]);
        *(uint4*)(z + (size_t)r * 512 + c) = pv;
      } else if (cg < 4) {
        float* qp = q + (size_t)r * 32 + cg * 8;
        *(float4*)qp = make_float4(acc[i][0], acc[i][1], acc[i][2], acc[i][3]);
        *(float4*)(qp + 4) = make_float4(acc[i][4], acc[i][5], acc[i][6], acc[i][7]);
      }
    }
  }
}

// ---------------- edge GEMM + fused f_out epilogue (edges in dst-sorted order) -----------
template <int K, bool STORE, bool ABF>
__global__ __launch_bounds__(256, 2) void gemm_fout_kernel(
    const void* __restrict__ Ap, const float* __restrict__ W, const float* __restrict__ bias,
    const ush* __restrict__ hs, const ush* __restrict__ hd, const int* __restrict__ src_s,
    const int* __restrict__ dst_s, const float* __restrict__ attn, ush* __restrict__ fstore,
    float* __restrict__ logit) {
  __shared__ float sA[128][K + 1];
  __shared__ float sW[K][64];
  int t = threadIdx.x;
  int r0 = blockIdx.x * 128;
  for (int i = t; i < K * 16; i += 256) ((float4*)sW)[i] = ((const float4*)W)[i];
  if (ABF) {
    const ush* A = (const ush*)Ap;
    for (int i = t; i < 128 * (K / 8); i += 256) {
      int rr = i / (K / 8), cc = i % (K / 8);
      uint4 v = (r0 + rr < NE) ? ((const uint4*)(A + (size_t)(r0 + rr) * K))[cc]
                               : make_uint4(0, 0, 0, 0);
      float* dp = &sA[rr][cc * 8];
      dp[0] = bf2f(v.x & 0xffff); dp[1] = bf2f(v.x >> 16);
      dp[2] = bf2f(v.y & 0xffff); dp[3] = bf2f(v.y >> 16);
      dp[4] = bf2f(v.z & 0xffff); dp[5] = bf2f(v.z >> 16);
      dp[6] = bf2f(v.w & 0xffff); dp[7] = bf2f(v.w >> 16);
    }
  } else {
    const float* A = (const float*)Ap;
    for (int i = t; i < 128 * (K / 4); i += 256) {
      int rr = i / (K / 4), cc = i % (K / 4);
      float4 v = (r0 + rr < NE) ? ((const float4*)(A + (size_t)(r0 + rr) * K))[cc]
                                : make_float4(0.f, 0.f, 0.f, 0.f);
      sA[rr][cc * 4 + 0] = v.x;
      sA[rr][cc * 4 + 1] = v.y;
      sA[rr][cc * 4 + 2] = v.z;
      sA[rr][cc * 4 + 3] = v.w;
    }
  }
  __syncthreads();
  int rg = t >> 3, cg = t & 7;
  float acc[4][8];
#pragma unroll
  for (int i = 0; i < 4; ++i)
#pragma unroll
    for (int j = 0; j < 8; ++j) acc[i][j] = 0.f;
#pragma unroll 8
  for (int k = 0; k < K; ++k) {
    float a0 = sA[rg * 4 + 0][k], a1 = sA[rg * 4 + 1][k];
    float a2 = sA[rg * 4 + 2][k], a3 = sA[rg * 4 + 3][k];
    float4 wA = *(const float4*)&sW[k][cg * 8];
    float4 wB = *(const float4*)&sW[k][cg * 8 + 4];
#pragma unroll
    for (int i = 0; i < 4; ++i) {
      float a = i == 0 ? a0 : i == 1 ? a1 : i == 2 ? a2 : a3;
      acc[i][0] = fmaf(a, wA.x, acc[i][0]); acc[i][1] = fmaf(a, wA.y, acc[i][1]);
      acc[i][2] = fmaf(a, wA.z, acc[i][2]); acc[i][3] = fmaf(a, wA.w, acc[i][3]);
      acc[i][4] = fmaf(a, wB.x, acc[i][4]); acc[i][5] = fmaf(a, wB.y, acc[i][5]);
      acc[i][6] = fmaf(a, wB.z, acc[i][6]); acc[i][7] = fmaf(a, wB.w, acc[i][7]);
    }
  }
  float bv[8], av[8];
#pragma unroll
  for (int j = 0; j < 8; ++j) {
    bv[j] = bias[cg * 8 + j];
    av[j] = attn[cg * 8 + j];
  }
#pragma unroll
  for (int i = 0; i < 4; ++i) {
    int r = r0 + rg * 4 + i;
    if (r < NE) {
      int s = src_s[r], d = dst_s[r];
      uint4 hv = *(const uint4*)(hs + (size_t)s * 64 + cg * 8);
      uint4 dv = *(const uint4*)(hd + (size_t)d * 64 + cg * 8);
      float fo[8];
      fo[0] = acc[i][0] + bf2f(hv.x & 0xffff) + bf2f(dv.x & 0xffff) + bv[0];
      fo[1] = acc[i][1] + bf2f(hv.x >> 16)    + bf2f(dv.x >> 16)    + bv[1];
      fo[2] = acc[i][2] + bf2f(hv.y & 0xffff) + bf2f(dv.y & 0xffff) + bv[2];
      fo[3] = acc[i][3] + bf2f(hv.y >> 16)    + bf2f(dv.y >> 16)    + bv[3];
      fo[4] = acc[i][4] + bf2f(hv.z & 0xffff) + bf2f(dv.z & 0xffff) + bv[4];
      fo[5] = acc[i][5] + bf2f(hv.z >> 16)    + bf2f(dv.z >> 16)    + bv[5];
      fo[6] = acc[i][6] + bf2f(hv.w & 0xffff) + bf2f(dv.w & 0xffff) + bv[6];
      fo[7] = acc[i][7] + bf2f(hv.w >> 16)    + bf2f(dv.w >> 16)    + bv[7];
      float p = 0.f;
#pragma unroll
      for (int j = 0; j < 8; ++j) {
        fo[j] = fo[j] >= 0.f ? fo[j] : 0.01f * fo[j];  // LeakyReLU
        p = fmaf(fo[j], av[j], p);
      }
      if (STORE) {
        uint4 pv;
        pv.x = pack2(fo[0], fo[1]);
        pv.y = pack2(fo[2], fo[3]);
        pv.z = pack2(fo[4], fo[5]);
        pv.w = pack2(fo[6], fo[7]);
        *(uint4*)(fstore + (size_t)r * 64 + cg * 8) = pv;
      }
      p += __shfl_xor(p, 1, 64);
      p += __shfl_xor(p, 2, 64);
      p += __shfl_xor(p, 4, 64);
      if (cg == 0) logit[r] = p;
    }
  }
}

// ---------------- EGAT: gather-aggregate, logits sequential (dst-sorted) -----------------
__global__ void agg_gather_kernel(const ush* __restrict__ hn, const float* __restrict__ logit,
                                  const int* __restrict__ rowptr, const int* __restrict__ deg,
                                  const int* __restrict__ src_s, float* __restrict__ hnew) {
  int wave = (blockIdx.x * blockDim.x + threadIdx.x) >> 6;
  int lane = threadIdx.x & 63;
  if (wave >= NN) return;
  int n = wave, d = deg[n], r0 = rowptr[n];
  if (d == 0) {
    hnew[(size_t)n * 64 + lane] = 0.f;
    return;
  }
  float m = -3.0e38f;
  for (int j = 0; j < d; ++j) m = fmaxf(m, logit[r0 + j]);
  float sum0 = 0.f, acc0 = 0.f, sum1 = 0.f, acc1 = 0.f;
  int j = 0;
  for (; j + 1 < d; j += 2) {
    int jj0 = r0 + j, jj1 = r0 + j + 1;
    int s0 = src_s[jj0], s1 = src_s[jj1];
    float w0 = __expf(logit[jj0] - m);
    float w1 = __expf(logit[jj1] - m);
    float v0 = bf2f(hn[(size_t)s0 * 64 + lane]);
    float v1 = bf2f(hn[(size_t)s1 * 64 + lane]);
    sum0 += w0; acc0 = fmaf(w0, v0, acc0);
    sum1 += w1; acc1 = fmaf(w1, v1, acc1);
  }
  if (j < d) {
    int jj = r0 + j;
    float w = __expf(logit[jj] - m);
    sum0 += w;
    acc0 = fmaf(w, bf2f(hn[(size_t)src_s[jj] * 64 + lane]), acc0);
  }
  hnew[(size_t)n * 64 + lane] = (acc0 + acc1) / (sum0 + sum1);
}

// ---------------- NNConv stage 2 (gather, 4-edge ILP, ef sequential) ----------------
__global__ void nnconv_gather_kernel(const ush* __restrict__ z, const float* __restrict__ q,
                                     const float* __restrict__ ef_s, const int* __restrict__ rowptr,
                                     const int* __restrict__ deg, const int* __restrict__ src_s,
                                     float* __restrict__ sArr) {
  int wave = (blockIdx.x * blockDim.x + threadIdx.x) >> 6;
  int lane = threadIdx.x & 63;
  if (wave >= NN) return;
  int n = wave, d = deg[n], r0 = rowptr[n];
  int o = lane >> 1, half = lane & 1;
  float acc0 = 0.f, acc1 = 0.f, acc2 = 0.f, acc3 = 0.f;
  int j = 0;
  for (; j + 3 < d; j += 4) {
#pragma unroll
    for (int u = 0; u < 4; ++u) {
      int jj = r0 + j + u;
      int s = src_s[jj];
      const float4* ep = (const float4*)(ef_s + (size_t)jj * 16 + half * 8);
      float4 ea = ep[0], eb = ep[1];
      uint4 zv = *(const uint4*)(z + (size_t)s * 512 + lane * 8);
      float a = (u == 0) ? acc0 : (u == 1) ? acc1 : (u == 2) ? acc2 : acc3;
      a = fmaf(ea.x, bf2f(zv.x & 0xffff), a);
      a = fmaf(ea.y, bf2f(zv.x >> 16), a);
      a = fmaf(ea.z, bf2f(zv.y & 0xffff), a);
      a = fmaf(ea.w, bf2f(zv.y >> 16), a);
      a = fmaf(eb.x, bf2f(zv.z & 0xffff), a);
      a = fmaf(eb.y, bf2f(zv.z >> 16), a);
      a = fmaf(eb.z, bf2f(zv.w & 0xffff), a);
      a = fmaf(eb.w, bf2f(zv.w >> 16), a);
      if (half == 0) a += q[(size_t)s * 32 + o];
      if (u == 0) acc0 = a; else if (u == 1) acc1 = a; else if (u == 2) acc2 = a; else acc3 = a;
    }
  }
  for (; j < d; ++j) {
    int jj = r0 + j;
    int s = src_s[jj];
    const float4* ep = (const float4*)(ef_s + (size_t)jj * 16 + half * 8);
    float4 ea = ep[0], eb = ep[1];
    uint4 zv = *(const uint4*)(z + (size_t)s * 512 + lane * 8);
    acc0 = fmaf(ea.x, bf2f(zv.x & 0xffff), acc0);
    acc0 = fmaf(ea.y, bf2f(zv.x >> 16), acc0);
    acc0 = fmaf(ea.z, bf2f(zv.y & 0xffff), acc0);
    acc0 = fmaf(ea.w, bf2f(zv.y >> 16), acc0);
    acc0 = fmaf(eb.x, bf2f(zv.z & 0xffff), acc0);
    acc0 = fmaf(eb.y, bf2f(zv.z >> 16), acc0);
    acc0 = fmaf(eb.z, bf2f(zv.w & 0xffff), acc0);
    acc0 = fmaf(eb.w, bf2f(zv.w >> 16), acc0);
    if (half == 0) acc0 += q[(size_t)s * 32 + o];
  }
  float acc = (acc0 + acc1) + (acc2 + acc3);
  acc += __shfl_xor(acc, 1, 64);
  if (half == 0) sArr[(size_t)n * 32 + o] = acc;
}

// ---------------- combine node_features + gate logit (fused; wave per node) --------------
__global__ void combine_gate_kernel(const float* __restrict__ hfin, const float* __restrict__ sArr,
                                    const int* __restrict__ deg, const float* __restrict__ nn_bias,
                                    const float* __restrict__ gate_w, const float* __restrict__ gate_b,
                                    float* __restrict__ out, float* __restrict__ g) {
  int wave = (blockIdx.x * blockDim.x + threadIdx.x) >> 6;
  int lane = threadIdx.x & 63;
  if (wave >= NN) return;
  int n = wave;
  float v0 = hfin[(size_t)n * 64 + lane];
  int c1 = lane + 64;
  float v1 = (c1 < 96)
                 ? sArr[(size_t)n * 32 + (c1 - 64)] / fmaxf((float)deg[n], 1.0f) + nn_bias[c1 - 64]
                 : 0.f;
  out[(size_t)n * 128 + lane] = v0;
  out[(size_t)n * 128 + c1] = v1;
  float p = v0 * gate_w[lane] + ((c1 < 96) ? v1 * gate_w[c1] : 0.f);
#pragma unroll
  for (int off = 32; off; off >>= 1) p += __shfl_xor(p, off, 64);
  if (lane == 0) g[n] = p + gate_b[0];
}

// ---------------- max over g (block-reduced, 1 atomic per block) ----------------
__global__ void gate_max_kernel(const float* __restrict__ g, unsigned* __restrict__ gmax) {
  int tid = blockIdx.x * blockDim.x + threadIdx.x;
  int stride = gridDim.x * blockDim.x;
  float v = -3.0e38f;
  for (int n = tid; n < NN; n += stride) v = fmaxf(v, g[n]);
#pragma unroll
  for (int off = 32; off; off >>= 1) v = fmaxf(v, __shfl_xor(v, off, 64));
  __shared__ float sm[4];
  int lane = threadIdx.x & 63, wid = threadIdx.x >> 6;
  if (lane == 0) sm[wid] = v;
  __syncthreads();
  if (threadIdx.x == 0) {
    float m = fmaxf(fmaxf(sm[0], sm[1]), fmaxf(sm[2], sm[3]));
    atomicMax(gmax, ord_enc(m));
  }
}

// ---------------- pooling: exp + weighted accumulate (fused) ----------------
__global__ void pool_exp_kernel(const float* __restrict__ nf, const float* __restrict__ g,
                                const unsigned* __restrict__ gmax, float* __restrict__ gacc,
                                float* __restrict__ gsum) {
  int o = threadIdx.x;  // blockDim = 128
  float m = ord_dec(*gmax);
  float acc = 0.f, ws = 0.f;
  for (int n = blockIdx.x; n < NN; n += gridDim.x) {
    float w = __expf(g[n] - m);
    ws += w;
    acc += w * nf[(size_t)n * 128 + o];
  }
  atomicAdd(gacc + o, acc);
  if (o == 0) atomicAdd(gsum, ws);
}

__global__ void finalize_kernel(const float* __restrict__ gacc, const float* __restrict__ gsum,
                                float* __restrict__ out) {
  int o = threadIdx.x;
  if (o < 128) out[(size_t)NN * 128 + o] = gacc[o] / gsum[0];
}

extern "C" void kernel_launch(void* const* d_in, const int* in_sizes, int n_in,
                              void* d_out, int out_size, void* d_ws, size_t ws_size,
                              hipStream_t stream) {
  const float* face    = (const float*)d_in[0];
  const float* ef      = (const float*)d_in[1];
  const float* fp_w    = (const float*)d_in[2];
  const float* fp_b    = (const float*)d_in[3];
  const float* ep_w    = (const float*)d_in[4];
  const float* ep_b    = (const float*)d_in[5];
  const float* nn_w    = (const float*)d_in[6];
  const float* nn_b    = (const float*)d_in[7];
  const float* nn_bias = (const float*)d_in[8];
  const float* gate_w  = (const float*)d_in[9];
  const float* gate_b  = (const float*)d_in[10];
  const int*   src     = (const int*)d_in[11];
  const int*   dst     = (const int*)d_in[12];
  const float* e1_attn = (const float*)d_in[17];
  const float* e2_ni   = (const float*)d_in[19];
  const float* e2_nj   = (const float*)d_in[20];
  const float* e2_fij  = (const float*)d_in[21];
  const float* e2_node = (const float*)d_in[22];
  const float* e2_attn = (const float*)d_in[23];
  const float* e2_bias = (const float*)d_in[24];
  float* out = (float*)d_out;

  char* p = (char*)d_ws;
  auto alloc = [&](size_t nfloats) {
    float* r = (float*)p;
    p += ((nfloats * 4 + 255) / 256) * 256;
    return r;
  };
  float* h0 = alloc((size_t)NN * 64);   // layer-2 output
  float* h1 = alloc((size_t)NN * 64);   // layer-1 output; q aliases after EGAT
  char* regionC = p;                    // hs16|hd16|hn16|f116 = 61.4 MB, dead after EGAT
  ush* hs16 = (ush*)alloc((size_t)NN * 32);   // NN*64 bf16
  ush* hd16 = (ush*)alloc((size_t)NN * 32);
  ush* hn16 = (ush*)alloc((size_t)NN * 32);
  ush* f116 = (ush*)alloc((size_t)NE * 32);   // NE*64 bf16 (dst-sorted order)
  float* logit = alloc(NE);                   // dst-sorted order
  float* sArr  = alloc((size_t)NN * 32);
  float* g     = alloc(NN);
  float* gacc  = alloc(128);
  float* gsum  = alloc(1);
  unsigned* gmax = (unsigned*)alloc(1);
  float* fold  = alloc(7424);
  float* W2    = alloc(32 * 576);
  // dst-CSR
  int* deg    = (int*)alloc(NN);
  int* rowptr = (int*)alloc(NN);
  int* cursor = (int*)alloc(NN);
  int* partial = (int*)alloc(256);
  int* src_s  = (int*)alloc(NE);
  int* dst_s  = (int*)alloc(NE);
  int* eid_s  = (int*)alloc(NE);
  float* ef_s = alloc((size_t)NE * 16);       // permuted edge features
  ush* z16 = (ush*)regionC;             // NN*512 bf16 = 61.44 MB == regionC exactly
  float* q = h1;                        // NN*32 <= h1's NN*64, h1 dead post-EGAT

  const float* Wf1  = fold;
  const float* b1f  = fold + 1024;
  const float* Wni1 = fold + 1088;
  const float* Wnj1 = fold + 3136;
  const float* Wno1 = fold + 5184;
  const float* bni1 = fold + 7232;
  const float* bnj1 = fold + 7296;
  const float* bno1 = fold + 7360;

  const int B = 256;
  const int NGB = cdiv(NN, 128);
  const int EGB = cdiv(NE, 128);
  const int NB256 = cdiv(NN, 256);

  // ---- CSR build (dst-sorted) + edge permutation ----
  hipMemsetAsync(deg, 0, NN * 4, stream);
  deg_kernel<<<cdiv(NE, B), B, 0, stream>>>(dst, deg);
  scan1_kernel<<<NB256, 256, 0, stream>>>(deg, rowptr, partial);
  scan2_kernel<<<1, 256, 0, stream>>>(partial, NB256);
  scan3_kernel<<<NB256, 256, 0, stream>>>(rowptr, partial, cursor);
  scatter_dst_kernel<<<cdiv(NE, B), B, 0, stream>>>(src, dst, cursor, src_s, dst_s, eid_s);
  permute_ef_kernel<<<cdiv(NE * 4, B), B, 0, stream>>>(ef, eid_s, ef_s);

  // folded weights + nn_w transpose (tiny)
  fold_kernel<<<29, B, 0, stream>>>(fp_w, fp_b, ep_w, ep_b,
                                    (const float*)d_in[15], (const float*)d_in[18],
                                    (const float*)d_in[13], (const float*)d_in[14],
                                    (const float*)d_in[16], fold);
  nnwt_kernel<<<72, B, 0, stream>>>(nn_w, nn_b, W2);

  // ---- EGAT layer 1 (edges processed in dst-sorted order) ----
  gemm3_kernel<32, true><<<dim3(NGB, 3), B, 0, stream>>>(face, Wni1, Wnj1, Wno1, bni1, bnj1,
                                                         bno1, hs16, hd16, hn16, NN);
  gemm_fout_kernel<16, true, false><<<EGB, B, 0, stream>>>(ef_s, Wf1, b1f, hs16, hd16, src_s,
                                                           dst_s, e1_attn, f116, logit);
  agg_gather_kernel<<<cdiv(NN * 64, B), B, 0, stream>>>(hn16, logit, rowptr, deg, src_s, h1);

  // ---- EGAT layer 2 ----
  gemm3_kernel<64, false><<<dim3(NGB, 3), B, 0, stream>>>(h1, e2_ni, e2_nj, e2_node, nullptr,
                                                          nullptr, nullptr, hs16, hd16, hn16, NN);
  gemm_fout_kernel<64, false, true><<<EGB, B, 0, stream>>>(f116, e2_fij, e2_bias, hs16, hd16,
                                                           src_s, dst_s, e2_attn, nullptr, logit);
  agg_gather_kernel<<<cdiv(NN * 64, B), B, 0, stream>>>(hn16, logit, rowptr, deg, src_s, h0);

  // ---- NNConv (z16/q alias dead EGAT buffers — must run after EGAT) ----
  gemm_zq_kernel<<<dim3(NGB, 9), B, 0, stream>>>(face, W2, z16, q, NN);
  nnconv_gather_kernel<<<cdiv(NN * 64, B), B, 0, stream>>>(z16, q, ef_s, rowptr, deg, src_s,
                                                           sArr);

  // ---- combine node features + gate logits ----
  hipMemsetAsync(gacc, 0, 128 * 4, stream);
  hipMemsetAsync(gsum, 0, 4, stream);
  hipMemsetAsync(gmax, 0, 4, stream);
  combine_gate_kernel<<<cdiv(NN * 64, B), B, 0, stream>>>(h0, sArr, deg, nn_bias, gate_w,
                                                          gate_b, out, g);
  gate_max_kernel<<<128, B, 0, stream>>>(g, gmax);
  pool_exp_kernel<<<512, 128, 0, stream>>>(out, g, gmax, gacc, gsum);
  finalize_kernel<<<1, 128, 0, stream>>>(gacc, gsum, out);
}

// Round 12
// 415.347 us; speedup vs baseline: 1.2074x; 1.0253x over previous
//
#include <hip/hip_runtime.h>

#define NN 60000
#define NE 300000
typedef unsigned short ush;

static inline int cdiv(int a, int b) { return (a + b - 1) / b; }

__device__ inline unsigned ord_enc(float x) {
  unsigned u = __float_as_uint(x);
  return (u & 0x80000000u) ? ~u : (u | 0x80000000u);
}
__device__ inline float ord_dec(unsigned u) {
  return __uint_as_float((u & 0x80000000u) ? (u & 0x7fffffffu) : ~u);
}
__device__ inline float bf2f(unsigned u16) { return __uint_as_float(u16 << 16); }
__device__ inline ush f2bf(float x) {
  unsigned u = __float_as_uint(x);
  return (ush)((u + 0x7FFFu + ((u >> 16) & 1u)) >> 16);
}
__device__ inline unsigned pack2(float lo, float hi) {
  return ((unsigned)f2bf(hi) << 16) | (unsigned)f2bf(lo);
}
__device__ inline float dot8(float4 ea, float4 eb, uint4 zv) {
  float a = ea.x * bf2f(zv.x & 0xffff);
  a = fmaf(ea.y, bf2f(zv.x >> 16), a);
  a = fmaf(ea.z, bf2f(zv.y & 0xffff), a);
  a = fmaf(ea.w, bf2f(zv.y >> 16), a);
  a = fmaf(eb.x, bf2f(zv.z & 0xffff), a);
  a = fmaf(eb.y, bf2f(zv.z >> 16), a);
  a = fmaf(eb.z, bf2f(zv.w & 0xffff), a);
  a = fmaf(eb.w, bf2f(zv.w >> 16), a);
  return a;
}

// ================= CSR build (dst-sorted) =================
__global__ void deg_kernel(const int* __restrict__ key, int* __restrict__ deg) {
  int e = blockIdx.x * blockDim.x + threadIdx.x;
  if (e < NE) atomicAdd(deg + key[e], 1);
}

__global__ void scan1_kernel(const int* __restrict__ deg, int* __restrict__ rowptr,
                             int* __restrict__ partial) {
  __shared__ int s[256];
  int i = blockIdx.x * 256 + threadIdx.x;
  int v = (i < NN) ? deg[i] : 0;
  s[threadIdx.x] = v;
  __syncthreads();
  for (int off = 1; off < 256; off <<= 1) {
    int t = (threadIdx.x >= off) ? s[threadIdx.x - off] : 0;
    __syncthreads();
    s[threadIdx.x] += t;
    __syncthreads();
  }
  if (i < NN) rowptr[i] = s[threadIdx.x] - v;
  if (threadIdx.x == 255) partial[blockIdx.x] = s[255];
}

__global__ void scan2_kernel(int* __restrict__ partial, int nb) {
  __shared__ int s[256];
  int v = (threadIdx.x < nb) ? partial[threadIdx.x] : 0;
  s[threadIdx.x] = v;
  __syncthreads();
  for (int off = 1; off < 256; off <<= 1) {
    int t = (threadIdx.x >= off) ? s[threadIdx.x - off] : 0;
    __syncthreads();
    s[threadIdx.x] += t;
    __syncthreads();
  }
  if (threadIdx.x < nb) partial[threadIdx.x] = s[threadIdx.x] - v;
}

__global__ void scan3_kernel(int* __restrict__ rowptr, const int* __restrict__ partial,
                             int* __restrict__ cursor) {
  int i = blockIdx.x * 256 + threadIdx.x;
  if (i < NN) {
    int r = rowptr[i] + partial[blockIdx.x];
    rowptr[i] = r;
    cursor[i] = r;
  }
}

__global__ void scatter_dst_kernel(const int* __restrict__ src, const int* __restrict__ dst,
                                   int* __restrict__ cursor, int* __restrict__ src_s,
                                   int* __restrict__ dst_s, int* __restrict__ eid_s) {
  int e = blockIdx.x * blockDim.x + threadIdx.x;
  if (e >= NE) return;
  int d = dst[e];
  int j = atomicAdd(cursor + d, 1);
  src_s[j] = src[e];
  dst_s[j] = d;
  eid_s[j] = e;
}

// permute ef rows into dst-sorted order (sequential write, gathered read)
__global__ void permute_ef_kernel(const float* __restrict__ ef, const int* __restrict__ eid_s,
                                  float* __restrict__ ef_s) {
  int j = blockIdx.x * blockDim.x + threadIdx.x;
  if (j >= NE * 4) return;
  int slot = j >> 2, c = j & 3;
  int e = eid_s[slot];
  ((float4*)ef_s)[(size_t)slot * 4 + c] = ((const float4*)ef)[(size_t)e * 4 + c];
}

// ---------------- fold: precompute folded weight products (7424 dots of length 64) -------
__global__ void fold_kernel(const float* __restrict__ fp_w, const float* __restrict__ fp_b,
                            const float* __restrict__ ep_w, const float* __restrict__ ep_b,
                            const float* __restrict__ fij, const float* __restrict__ ebias,
                            const float* __restrict__ ni, const float* __restrict__ nj,
                            const float* __restrict__ node, float* __restrict__ fold) {
  int t = blockIdx.x * blockDim.x + threadIdx.x;
  if (t >= 7424) return;
  int o = t & 63;
  const float* A;
  const float* B;
  float init = 0.f;
  if (t < 1024)      { A = ep_w + (size_t)(t >> 6) * 64; B = fij + o; }
  else if (t < 1088) { A = ep_b; B = fij + o; init = ebias[o]; }
  else if (t < 3136) { A = fp_w + (size_t)((t - 1088) >> 6) * 64; B = ni + o; }
  else if (t < 5184) { A = fp_w + (size_t)((t - 3136) >> 6) * 64; B = nj + o; }
  else if (t < 7232) { A = fp_w + (size_t)((t - 5184) >> 6) * 64; B = node + o; }
  else if (t < 7296) { A = fp_b; B = ni + o; }
  else if (t < 7360) { A = fp_b; B = nj + o; }
  else               { A = fp_b; B = node + o; }
  float a = init;
  for (int i = 0; i < 64; ++i) a = fmaf(A[i], B[(size_t)i * 64], a);
  fold[t] = a;
}

// ---------------- transpose nn_w/nn_b into W2[32][576] ----------------
__global__ void nnwt_kernel(const float* __restrict__ nn_w, const float* __restrict__ nn_b,
                            float* __restrict__ W2) {
  int t = blockIdx.x * blockDim.x + threadIdx.x;
  if (t >= 32 * 576) return;
  int i = t / 576, c = t % 576;
  float v = 0.f;
  if (c < 512) v = nn_w[(size_t)(c & 15) * 1024 + i * 32 + (c >> 4)];
  else if (c < 544) v = nn_b[i * 32 + (c - 512)];
  W2[t] = v;
}

// ---------------- tiled GEMM (rows x K) @ (K x 64) -> bf16 out; 3 weight sets ------------
template <int K, bool BIAS>
__global__ __launch_bounds__(256, 2) void gemm3_kernel(
    const float* __restrict__ A, const float* __restrict__ W0, const float* __restrict__ W1,
    const float* __restrict__ W2, const float* __restrict__ b0, const float* __restrict__ b1,
    const float* __restrict__ b2, ush* __restrict__ o0, ush* __restrict__ o1,
    ush* __restrict__ o2, int rows) {
  __shared__ float sA[128][K + 1];
  __shared__ float sW[K][64];
  const float* W = blockIdx.y == 0 ? W0 : blockIdx.y == 1 ? W1 : W2;
  const float* bb = blockIdx.y == 0 ? b0 : blockIdx.y == 1 ? b1 : b2;
  ush* out = blockIdx.y == 0 ? o0 : blockIdx.y == 1 ? o1 : o2;
  int t = threadIdx.x;
  int r0 = blockIdx.x * 128;
  for (int i = t; i < K * 16; i += 256) ((float4*)sW)[i] = ((const float4*)W)[i];
  for (int i = t; i < 128 * (K / 4); i += 256) {
    int rr = i / (K / 4), cc = i % (K / 4);
    float4 v = (r0 + rr < rows) ? ((const float4*)(A + (size_t)(r0 + rr) * K))[cc]
                                : make_float4(0.f, 0.f, 0.f, 0.f);
    sA[rr][cc * 4 + 0] = v.x;
    sA[rr][cc * 4 + 1] = v.y;
    sA[rr][cc * 4 + 2] = v.z;
    sA[rr][cc * 4 + 3] = v.w;
  }
  __syncthreads();
  int rg = t >> 3, cg = t & 7;
  float acc[4][8];
#pragma unroll
  for (int i = 0; i < 4; ++i)
#pragma unroll
    for (int j = 0; j < 8; ++j) acc[i][j] = 0.f;
#pragma unroll 8
  for (int k = 0; k < K; ++k) {
    float a0 = sA[rg * 4 + 0][k], a1 = sA[rg * 4 + 1][k];
    float a2 = sA[rg * 4 + 2][k], a3 = sA[rg * 4 + 3][k];
    float4 wA = *(const float4*)&sW[k][cg * 8];
    float4 wB = *(const float4*)&sW[k][cg * 8 + 4];
#pragma unroll
    for (int i = 0; i < 4; ++i) {
      float a = i == 0 ? a0 : i == 1 ? a1 : i == 2 ? a2 : a3;
      acc[i][0] = fmaf(a, wA.x, acc[i][0]); acc[i][1] = fmaf(a, wA.y, acc[i][1]);
      acc[i][2] = fmaf(a, wA.z, acc[i][2]); acc[i][3] = fmaf(a, wA.w, acc[i][3]);
      acc[i][4] = fmaf(a, wB.x, acc[i][4]); acc[i][5] = fmaf(a, wB.y, acc[i][5]);
      acc[i][6] = fmaf(a, wB.z, acc[i][6]); acc[i][7] = fmaf(a, wB.w, acc[i][7]);
    }
  }
  float bv[8];
#pragma unroll
  for (int j = 0; j < 8; ++j) bv[j] = BIAS ? bb[cg * 8 + j] : 0.f;
#pragma unroll
  for (int i = 0; i < 4; ++i) {
    int r = r0 + rg * 4 + i;
    if (r < rows) {
      uint4 pv;
      pv.x = pack2(acc[i][0] + bv[0], acc[i][1] + bv[1]);
      pv.y = pack2(acc[i][2] + bv[2], acc[i][3] + bv[3]);
      pv.z = pack2(acc[i][4] + bv[4], acc[i][5] + bv[5]);
      pv.w = pack2(acc[i][6] + bv[6], acc[i][7] + bv[7]);
      *(uint4*)(out + (size_t)r * 64 + cg * 8) = pv;
    }
  }
}

// ---------------- zq as tiled GEMM: face(NNx32) @ W2(32x576) -> z bf16 | q f32 -----------
__global__ __launch_bounds__(256, 2) void gemm_zq_kernel(
    const float* __restrict__ A, const float* __restrict__ W2, ush* __restrict__ z,
    float* __restrict__ q, int rows) {
  __shared__ float sA[128][33];
  __shared__ float sW[32][64];
  int t = threadIdx.x;
  int r0 = blockIdx.x * 128;
  int c0 = blockIdx.y * 64;
  for (int i = t; i < 32 * 16; i += 256) {
    int ri = i / 16, cc = i % 16;
    float4 v = *(const float4*)(W2 + (size_t)ri * 576 + c0 + cc * 4);
    *(float4*)&sW[ri][cc * 4] = v;
  }
  for (int i = t; i < 128 * 8; i += 256) {
    int rr = i / 8, cc = i % 8;
    float4 v = (r0 + rr < rows) ? ((const float4*)(A + (size_t)(r0 + rr) * 32))[cc]
                                : make_float4(0.f, 0.f, 0.f, 0.f);
    sA[rr][cc * 4 + 0] = v.x;
    sA[rr][cc * 4 + 1] = v.y;
    sA[rr][cc * 4 + 2] = v.z;
    sA[rr][cc * 4 + 3] = v.w;
  }
  __syncthreads();
  int rg = t >> 3, cg = t & 7;
  float acc[4][8];
#pragma unroll
  for (int i = 0; i < 4; ++i)
#pragma unroll
    for (int j = 0; j < 8; ++j) acc[i][j] = 0.f;
#pragma unroll 8
  for (int k = 0; k < 32; ++k) {
    float a0 = sA[rg * 4 + 0][k], a1 = sA[rg * 4 + 1][k];
    float a2 = sA[rg * 4 + 2][k], a3 = sA[rg * 4 + 3][k];
    float4 wA = *(const float4*)&sW[k][cg * 8];
    float4 wB = *(const float4*)&sW[k][cg * 8 + 4];
#pragma unroll
    for (int i = 0; i < 4; ++i) {
      float a = i == 0 ? a0 : i == 1 ? a1 : i == 2 ? a2 : a3;
      acc[i][0] = fmaf(a, wA.x, acc[i][0]); acc[i][1] = fmaf(a, wA.y, acc[i][1]);
      acc[i][2] = fmaf(a, wA.z, acc[i][2]); acc[i][3] = fmaf(a, wA.w, acc[i][3]);
      acc[i][4] = fmaf(a, wB.x, acc[i][4]); acc[i][5] = fmaf(a, wB.y, acc[i][5]);
      acc[i][6] = fmaf(a, wB.z, acc[i][6]); acc[i][7] = fmaf(a, wB.w, acc[i][7]);
    }
  }
#pragma unroll
  for (int i = 0; i < 4; ++i) {
    int r = r0 + rg * 4 + i;
    if (r < rows) {
      if (blockIdx.y < 8) {
        int c = c0 + cg * 8;
        uint4 pv;
        pv.x = pack2(acc[i][0], acc[i][1]);
        pv.y = pack2(acc[i][2], acc[i][3]);
        pv.z = pack2(acc[i][4], acc[i][5]);
        pv.w = pack2(acc[i][6], acc[i][7]);
        *(uint4*)(z + (size_t)r * 512 + c) = pv;
      } else if (cg < 4) {
        float* qp = q + (size_t)r * 32 + cg * 8;
        *(float4*)qp = make_float4(acc[i][0], acc[i][1], acc[i][2], acc[i][3]);
        *(float4*)(qp + 4) = make_float4(acc[i][4], acc[i][5], acc[i][6], acc[i][7]);
      }
    }
  }
}

// ---------------- edge GEMM + fused f_out epilogue (edges in dst-sorted order) -----------
template <int K, bool STORE, bool ABF>
__global__ __launch_bounds__(256, 2) void gemm_fout_kernel(
    const void* __restrict__ Ap, const float* __restrict__ W, const float* __restrict__ bias,
    const ush* __restrict__ hs, const ush* __restrict__ hd, const int* __restrict__ src_s,
    const int* __restrict__ dst_s, const float* __restrict__ attn, ush* __restrict__ fstore,
    float* __restrict__ logit) {
  __shared__ float sA[128][K + 1];
  __shared__ float sW[K][64];
  int t = threadIdx.x;
  int r0 = blockIdx.x * 128;
  for (int i = t; i < K * 16; i += 256) ((float4*)sW)[i] = ((const float4*)W)[i];
  if (ABF) {
    const ush* A = (const ush*)Ap;
    for (int i = t; i < 128 * (K / 8); i += 256) {
      int rr = i / (K / 8), cc = i % (K / 8);
      uint4 v = (r0 + rr < NE) ? ((const uint4*)(A + (size_t)(r0 + rr) * K))[cc]
                               : make_uint4(0, 0, 0, 0);
      float* dp = &sA[rr][cc * 8];
      dp[0] = bf2f(v.x & 0xffff); dp[1] = bf2f(v.x >> 16);
      dp[2] = bf2f(v.y & 0xffff); dp[3] = bf2f(v.y >> 16);
      dp[4] = bf2f(v.z & 0xffff); dp[5] = bf2f(v.z >> 16);
      dp[6] = bf2f(v.w & 0xffff); dp[7] = bf2f(v.w >> 16);
    }
  } else {
    const float* A = (const float*)Ap;
    for (int i = t; i < 128 * (K / 4); i += 256) {
      int rr = i / (K / 4), cc = i % (K / 4);
      float4 v = (r0 + rr < NE) ? ((const float4*)(A + (size_t)(r0 + rr) * K))[cc]
                                : make_float4(0.f, 0.f, 0.f, 0.f);
      sA[rr][cc * 4 + 0] = v.x;
      sA[rr][cc * 4 + 1] = v.y;
      sA[rr][cc * 4 + 2] = v.z;
      sA[rr][cc * 4 + 3] = v.w;
    }
  }
  __syncthreads();
  int rg = t >> 3, cg = t & 7;
  float acc[4][8];
#pragma unroll
  for (int i = 0; i < 4; ++i)
#pragma unroll
    for (int j = 0; j < 8; ++j) acc[i][j] = 0.f;
#pragma unroll 8
  for (int k = 0; k < K; ++k) {
    float a0 = sA[rg * 4 + 0][k], a1 = sA[rg * 4 + 1][k];
    float a2 = sA[rg * 4 + 2][k], a3 = sA[rg * 4 + 3][k];
    float4 wA = *(const float4*)&sW[k][cg * 8];
    float4 wB = *(const float4*)&sW[k][cg * 8 + 4];
#pragma unroll
    for (int i = 0; i < 4; ++i) {
      float a = i == 0 ? a0 : i == 1 ? a1 : i == 2 ? a2 : a3;
      acc[i][0] = fmaf(a, wA.x, acc[i][0]); acc[i][1] = fmaf(a, wA.y, acc[i][1]);
      acc[i][2] = fmaf(a, wA.z, acc[i][2]); acc[i][3] = fmaf(a, wA.w, acc[i][3]);
      acc[i][4] = fmaf(a, wB.x, acc[i][4]); acc[i][5] = fmaf(a, wB.y, acc[i][5]);
      acc[i][6] = fmaf(a, wB.z, acc[i][6]); acc[i][7] = fmaf(a, wB.w, acc[i][7]);
    }
  }
  float bv[8], av[8];
#pragma unroll
  for (int j = 0; j < 8; ++j) {
    bv[j] = bias[cg * 8 + j];
    av[j] = attn[cg * 8 + j];
  }
#pragma unroll
  for (int i = 0; i < 4; ++i) {
    int r = r0 + rg * 4 + i;
    if (r < NE) {
      int s = src_s[r], d = dst_s[r];
      uint4 hv = *(const uint4*)(hs + (size_t)s * 64 + cg * 8);
      uint4 dv = *(const uint4*)(hd + (size_t)d * 64 + cg * 8);
      float fo[8];
      fo[0] = acc[i][0] + bf2f(hv.x & 0xffff) + bf2f(dv.x & 0xffff) + bv[0];
      fo[1] = acc[i][1] + bf2f(hv.x >> 16)    + bf2f(dv.x >> 16)    + bv[1];
      fo[2] = acc[i][2] + bf2f(hv.y & 0xffff) + bf2f(dv.y & 0xffff) + bv[2];
      fo[3] = acc[i][3] + bf2f(hv.y >> 16)    + bf2f(dv.y >> 16)    + bv[3];
      fo[4] = acc[i][4] + bf2f(hv.z & 0xffff) + bf2f(dv.z & 0xffff) + bv[4];
      fo[5] = acc[i][5] + bf2f(hv.z >> 16)    + bf2f(dv.z >> 16)    + bv[5];
      fo[6] = acc[i][6] + bf2f(hv.w & 0xffff) + bf2f(dv.w & 0xffff) + bv[6];
      fo[7] = acc[i][7] + bf2f(hv.w >> 16)    + bf2f(dv.w >> 16)    + bv[7];
      float p = 0.f;
#pragma unroll
      for (int j = 0; j < 8; ++j) {
        fo[j] = fo[j] >= 0.f ? fo[j] : 0.01f * fo[j];  // LeakyReLU
        p = fmaf(fo[j], av[j], p);
      }
      if (STORE) {
        uint4 pv;
        pv.x = pack2(fo[0], fo[1]);
        pv.y = pack2(fo[2], fo[3]);
        pv.z = pack2(fo[4], fo[5]);
        pv.w = pack2(fo[6], fo[7]);
        *(uint4*)(fstore + (size_t)r * 64 + cg * 8) = pv;
      }
      p += __shfl_xor(p, 1, 64);
      p += __shfl_xor(p, 2, 64);
      p += __shfl_xor(p, 4, 64);
      if (cg == 0) logit[r] = p;
    }
  }
}

// ---------------- EGAT: gather-aggregate, 4-deep load-then-FMA pipeline ------------------
__global__ __launch_bounds__(256, 4) void agg_gather_kernel(
    const ush* __restrict__ hn, const float* __restrict__ logit, const int* __restrict__ rowptr,
    const int* __restrict__ deg, const int* __restrict__ src_s, float* __restrict__ hnew) {
  int wave = (blockIdx.x * blockDim.x + threadIdx.x) >> 6;
  int lane = threadIdx.x & 63;
  if (wave >= NN) return;
  int n = wave, d = deg[n], r0 = rowptr[n];
  if (d == 0) {
    hnew[(size_t)n * 64 + lane] = 0.f;
    return;
  }
  float m = -3.0e38f;
  for (int j = 0; j < d; ++j) m = fmaxf(m, logit[r0 + j]);
  float sum = 0.f, acc0 = 0.f, acc1 = 0.f, acc2 = 0.f, acc3 = 0.f;
  int j = 0;
  for (; j + 3 < d; j += 4) {
    int jj = r0 + j;
    int s0 = src_s[jj + 0], s1 = src_s[jj + 1], s2 = src_s[jj + 2], s3 = src_s[jj + 3];
    float l0 = logit[jj + 0], l1 = logit[jj + 1], l2 = logit[jj + 2], l3 = logit[jj + 3];
    ush h0 = hn[(size_t)s0 * 64 + lane];
    ush h1 = hn[(size_t)s1 * 64 + lane];
    ush h2 = hn[(size_t)s2 * 64 + lane];
    ush h3 = hn[(size_t)s3 * 64 + lane];
    float w0 = __expf(l0 - m), w1 = __expf(l1 - m);
    float w2 = __expf(l2 - m), w3 = __expf(l3 - m);
    sum += (w0 + w1) + (w2 + w3);
    acc0 = fmaf(w0, bf2f(h0), acc0);
    acc1 = fmaf(w1, bf2f(h1), acc1);
    acc2 = fmaf(w2, bf2f(h2), acc2);
    acc3 = fmaf(w3, bf2f(h3), acc3);
  }
  for (; j < d; ++j) {
    int jj = r0 + j;
    float w = __expf(logit[jj] - m);
    sum += w;
    acc0 = fmaf(w, bf2f(hn[(size_t)src_s[jj] * 64 + lane]), acc0);
  }
  hnew[(size_t)n * 64 + lane] = ((acc0 + acc1) + (acc2 + acc3)) / sum;
}

// ---------------- NNConv stage 2 (gather, 4-deep load-then-FMA pipeline) -----------------
__global__ __launch_bounds__(256, 4) void nnconv_gather_kernel(
    const ush* __restrict__ z, const float* __restrict__ q, const float* __restrict__ ef_s,
    const int* __restrict__ rowptr, const int* __restrict__ deg, const int* __restrict__ src_s,
    float* __restrict__ sArr) {
  int wave = (blockIdx.x * blockDim.x + threadIdx.x) >> 6;
  int lane = threadIdx.x & 63;
  if (wave >= NN) return;
  int n = wave, d = deg[n], r0 = rowptr[n];
  int o = lane >> 1, half = lane & 1;
  float acc0 = 0.f, acc1 = 0.f, acc2 = 0.f, acc3 = 0.f;
  int j = 0;
  for (; j + 3 < d; j += 4) {
    int jj = r0 + j;
    int s0 = src_s[jj + 0], s1 = src_s[jj + 1], s2 = src_s[jj + 2], s3 = src_s[jj + 3];
    // issue all loads up front (kept in named regs -> outstanding in parallel)
    uint4 zv0 = *(const uint4*)(z + (size_t)s0 * 512 + lane * 8);
    uint4 zv1 = *(const uint4*)(z + (size_t)s1 * 512 + lane * 8);
    uint4 zv2 = *(const uint4*)(z + (size_t)s2 * 512 + lane * 8);
    uint4 zv3 = *(const uint4*)(z + (size_t)s3 * 512 + lane * 8);
    const float4* ep0 = (const float4*)(ef_s + (size_t)(jj + 0) * 16 + half * 8);
    const float4* ep1 = (const float4*)(ef_s + (size_t)(jj + 1) * 16 + half * 8);
    const float4* ep2 = (const float4*)(ef_s + (size_t)(jj + 2) * 16 + half * 8);
    const float4* ep3 = (const float4*)(ef_s + (size_t)(jj + 3) * 16 + half * 8);
    float4 ea0 = ep0[0], eb0 = ep0[1];
    float4 ea1 = ep1[0], eb1 = ep1[1];
    float4 ea2 = ep2[0], eb2 = ep2[1];
    float4 ea3 = ep3[0], eb3 = ep3[1];
    float q0 = 0.f, q1 = 0.f, q2 = 0.f, q3 = 0.f;
    if (half == 0) {
      q0 = q[(size_t)s0 * 32 + o];
      q1 = q[(size_t)s1 * 32 + o];
      q2 = q[(size_t)s2 * 32 + o];
      q3 = q[(size_t)s3 * 32 + o];
    }
    acc0 += dot8(ea0, eb0, zv0) + q0;
    acc1 += dot8(ea1, eb1, zv1) + q1;
    acc2 += dot8(ea2, eb2, zv2) + q2;
    acc3 += dot8(ea3, eb3, zv3) + q3;
  }
  for (; j < d; ++j) {
    int jj = r0 + j;
    int s = src_s[jj];
    const float4* ep = (const float4*)(ef_s + (size_t)jj * 16 + half * 8);
    float4 ea = ep[0], eb = ep[1];
    uint4 zv = *(const uint4*)(z + (size_t)s * 512 + lane * 8);
    float qv = (half == 0) ? q[(size_t)s * 32 + o] : 0.f;
    acc0 += dot8(ea, eb, zv) + qv;
  }
  float acc = (acc0 + acc1) + (acc2 + acc3);
  acc += __shfl_xor(acc, 1, 64);
  if (half == 0) sArr[(size_t)n * 32 + o] = acc;
}

// ---------------- combine node_features + gate logit (fused; wave per node) --------------
__global__ void combine_gate_kernel(const float* __restrict__ hfin, const float* __restrict__ sArr,
                                    const int* __restrict__ deg, const float* __restrict__ nn_bias,
                                    const float* __restrict__ gate_w, const float* __restrict__ gate_b,
                                    float* __restrict__ out, float* __restrict__ g) {
  int wave = (blockIdx.x * blockDim.x + threadIdx.x) >> 6;
  int lane = threadIdx.x & 63;
  if (wave >= NN) return;
  int n = wave;
  float v0 = hfin[(size_t)n * 64 + lane];
  int c1 = lane + 64;
  float v1 = (c1 < 96)
                 ? sArr[(size_t)n * 32 + (c1 - 64)] / fmaxf((float)deg[n], 1.0f) + nn_bias[c1 - 64]
                 : 0.f;
  out[(size_t)n * 128 + lane] = v0;
  out[(size_t)n * 128 + c1] = v1;
  float p = v0 * gate_w[lane] + ((c1 < 96) ? v1 * gate_w[c1] : 0.f);
#pragma unroll
  for (int off = 32; off; off >>= 1) p += __shfl_xor(p, off, 64);
  if (lane == 0) g[n] = p + gate_b[0];
}

// ---------------- max over g (block-reduced, 1 atomic per block) ----------------
__global__ void gate_max_kernel(const float* __restrict__ g, unsigned* __restrict__ gmax) {
  int tid = blockIdx.x * blockDim.x + threadIdx.x;
  int stride = gridDim.x * blockDim.x;
  float v = -3.0e38f;
  for (int n = tid; n < NN; n += stride) v = fmaxf(v, g[n]);
#pragma unroll
  for (int off = 32; off; off >>= 1) v = fmaxf(v, __shfl_xor(v, off, 64));
  __shared__ float sm[4];
  int lane = threadIdx.x & 63, wid = threadIdx.x >> 6;
  if (lane == 0) sm[wid] = v;
  __syncthreads();
  if (threadIdx.x == 0) {
    float m = fmaxf(fmaxf(sm[0], sm[1]), fmaxf(sm[2], sm[3]));
    atomicMax(gmax, ord_enc(m));
  }
}

// ---------------- pooling: exp + weighted accumulate (fused) ----------------
__global__ void pool_exp_kernel(const float* __restrict__ nf, const float* __restrict__ g,
                                const unsigned* __restrict__ gmax, float* __restrict__ gacc,
                                float* __restrict__ gsum) {
  int o = threadIdx.x;  // blockDim = 128
  float m = ord_dec(*gmax);
  float acc = 0.f, ws = 0.f;
  for (int n = blockIdx.x; n < NN; n += gridDim.x) {
    float w = __expf(g[n] - m);
    ws += w;
    acc += w * nf[(size_t)n * 128 + o];
  }
  atomicAdd(gacc + o, acc);
  if (o == 0) atomicAdd(gsum, ws);
}

__global__ void finalize_kernel(const float* __restrict__ gacc, const float* __restrict__ gsum,
                                float* __restrict__ out) {
  int o = threadIdx.x;
  if (o < 128) out[(size_t)NN * 128 + o] = gacc[o] / gsum[0];
}

extern "C" void kernel_launch(void* const* d_in, const int* in_sizes, int n_in,
                              void* d_out, int out_size, void* d_ws, size_t ws_size,
                              hipStream_t stream) {
  const float* face    = (const float*)d_in[0];
  const float* ef      = (const float*)d_in[1];
  const float* fp_w    = (const float*)d_in[2];
  const float* fp_b    = (const float*)d_in[3];
  const float* ep_w    = (const float*)d_in[4];
  const float* ep_b    = (const float*)d_in[5];
  const float* nn_w    = (const float*)d_in[6];
  const float* nn_b    = (const float*)d_in[7];
  const float* nn_bias = (const float*)d_in[8];
  const float* gate_w  = (const float*)d_in[9];
  const float* gate_b  = (const float*)d_in[10];
  const int*   src     = (const int*)d_in[11];
  const int*   dst     = (const int*)d_in[12];
  const float* e1_attn = (const float*)d_in[17];
  const float* e2_ni   = (const float*)d_in[19];
  const float* e2_nj   = (const float*)d_in[20];
  const float* e2_fij  = (const float*)d_in[21];
  const float* e2_node = (const float*)d_in[22];
  const float* e2_attn = (const float*)d_in[23];
  const float* e2_bias = (const float*)d_in[24];
  float* out = (float*)d_out;

  char* p = (char*)d_ws;
  auto alloc = [&](size_t nfloats) {
    float* r = (float*)p;
    p += ((nfloats * 4 + 255) / 256) * 256;
    return r;
  };
  float* h0 = alloc((size_t)NN * 64);   // layer-2 output
  float* h1 = alloc((size_t)NN * 64);   // layer-1 output; q aliases after EGAT
  char* regionC = p;                    // hs16|hd16|hn16|f116 = 61.4 MB, dead after EGAT
  ush* hs16 = (ush*)alloc((size_t)NN * 32);   // NN*64 bf16
  ush* hd16 = (ush*)alloc((size_t)NN * 32);
  ush* hn16 = (ush*)alloc((size_t)NN * 32);
  ush* f116 = (ush*)alloc((size_t)NE * 32);   // NE*64 bf16 (dst-sorted order)
  float* logit = alloc(NE);                   // dst-sorted order
  float* sArr  = alloc((size_t)NN * 32);
  float* g     = alloc(NN);
  float* gacc  = alloc(128);
  float* gsum  = alloc(1);
  unsigned* gmax = (unsigned*)alloc(1);
  float* fold  = alloc(7424);
  float* W2    = alloc(32 * 576);
  // dst-CSR
  int* deg    = (int*)alloc(NN);
  int* rowptr = (int*)alloc(NN);
  int* cursor = (int*)alloc(NN);
  int* partial = (int*)alloc(256);
  int* src_s  = (int*)alloc(NE);
  int* dst_s  = (int*)alloc(NE);
  int* eid_s  = (int*)alloc(NE);
  float* ef_s = alloc((size_t)NE * 16);       // permuted edge features
  ush* z16 = (ush*)regionC;             // NN*512 bf16 = 61.44 MB == regionC exactly
  float* q = h1;                        // NN*32 <= h1's NN*64, h1 dead post-EGAT

  const float* Wf1  = fold;
  const float* b1f  = fold + 1024;
  const float* Wni1 = fold + 1088;
  const float* Wnj1 = fold + 3136;
  const float* Wno1 = fold + 5184;
  const float* bni1 = fold + 7232;
  const float* bnj1 = fold + 7296;
  const float* bno1 = fold + 7360;

  const int B = 256;
  const int NGB = cdiv(NN, 128);
  const int EGB = cdiv(NE, 128);
  const int NB256 = cdiv(NN, 256);

  // ---- CSR build (dst-sorted) + edge permutation ----
  hipMemsetAsync(deg, 0, NN * 4, stream);
  deg_kernel<<<cdiv(NE, B), B, 0, stream>>>(dst, deg);
  scan1_kernel<<<NB256, 256, 0, stream>>>(deg, rowptr, partial);
  scan2_kernel<<<1, 256, 0, stream>>>(partial, NB256);
  scan3_kernel<<<NB256, 256, 0, stream>>>(rowptr, partial, cursor);
  scatter_dst_kernel<<<cdiv(NE, B), B, 0, stream>>>(src, dst, cursor, src_s, dst_s, eid_s);
  permute_ef_kernel<<<cdiv(NE * 4, B), B, 0, stream>>>(ef, eid_s, ef_s);

  // folded weights + nn_w transpose (tiny)
  fold_kernel<<<29, B, 0, stream>>>(fp_w, fp_b, ep_w, ep_b,
                                    (const float*)d_in[15], (const float*)d_in[18],
                                    (const float*)d_in[13], (const float*)d_in[14],
                                    (const float*)d_in[16], fold);
  nnwt_kernel<<<72, B, 0, stream>>>(nn_w, nn_b, W2);

  // ---- EGAT layer 1 (edges processed in dst-sorted order) ----
  gemm3_kernel<32, true><<<dim3(NGB, 3), B, 0, stream>>>(face, Wni1, Wnj1, Wno1, bni1, bnj1,
                                                         bno1, hs16, hd16, hn16, NN);
  gemm_fout_kernel<16, true, false><<<EGB, B, 0, stream>>>(ef_s, Wf1, b1f, hs16, hd16, src_s,
                                                           dst_s, e1_attn, f116, logit);
  agg_gather_kernel<<<cdiv(NN * 64, B), B, 0, stream>>>(hn16, logit, rowptr, deg, src_s, h1);

  // ---- EGAT layer 2 ----
  gemm3_kernel<64, false><<<dim3(NGB, 3), B, 0, stream>>>(h1, e2_ni, e2_nj, e2_node, nullptr,
                                                          nullptr, nullptr, hs16, hd16, hn16, NN);
  gemm_fout_kernel<64, false, true><<<EGB, B, 0, stream>>>(f116, e2_fij, e2_bias, hs16, hd16,
                                                           src_s, dst_s, e2_attn, nullptr, logit);
  agg_gather_kernel<<<cdiv(NN * 64, B), B, 0, stream>>>(hn16, logit, rowptr, deg, src_s, h0);

  // ---- NNConv (z16/q alias dead EGAT buffers — must run after EGAT) ----
  gemm_zq_kernel<<<dim3(NGB, 9), B, 0, stream>>>(face, W2, z16, q, NN);
  nnconv_gather_kernel<<<cdiv(NN * 64, B), B, 0, stream>>>(z16, q, ef_s, rowptr, deg, src_s,
                                                           sArr);

  // ---- combine node features + gate logits ----
  hipMemsetAsync(gacc, 0, 128 * 4, stream);
  hipMemsetAsync(gsum, 0, 4, stream);
  hipMemsetAsync(gmax, 0, 4, stream);
  combine_gate_kernel<<<cdiv(NN * 64, B), B, 0, stream>>>(h0, sArr, deg, nn_bias, gate_w,
                                                          gate_b, out, g);
  gate_max_kernel<<<128, B, 0, stream>>>(g, gmax);
  pool_exp_kernel<<<512, 128, 0, stream>>>(out, g, gmax, gacc, gsum);
  finalize_kernel<<<1, 128, 0, stream>>>(gacc, gsum, out);
}